// Round 6
// baseline (2766.052 us; speedup 1.0000x reference)
//
#include <hip/hip_runtime.h>
#include <hip/hip_fp16.h>
#include <cstddef>
#include <cstdint>

namespace {

constexpr int NPROT = 100000;
constexpr int EPROT = 1600000;
constexpr int NLIG  = 5000;
constexpr int ELIG  = 80000;

// ---------------- CSR construction ----------------

__global__ void hist_kernel(const int* __restrict__ dst, int* __restrict__ cnt, int e) {
  int i = blockIdx.x * 256 + threadIdx.x;
  if (i < e) atomicAdd(&cnt[dst[i]], 1);
}

// per-block (1024 elems) exclusive scan; also computes nrm = max(deg,1)^-0.5
__global__ void scan1_kernel(const int* __restrict__ cnt, int* __restrict__ rp,
                             int* __restrict__ bsum, float* __restrict__ nrm, int n) {
  __shared__ int wsum[4];
  int t = threadIdx.x;
  int base = blockIdx.x * 1024 + t * 4;
  int v0 = 0, v1 = 0, v2 = 0, v3 = 0;
  if (base + 3 < n) {
    int4 val = *(const int4*)(cnt + base);
    v0 = val.x; v1 = val.y; v2 = val.z; v3 = val.w;
  } else if (base < n) {
    v0 = cnt[base];
    if (base + 1 < n) v1 = cnt[base + 1];
    if (base + 2 < n) v2 = cnt[base + 2];
  }
  if (base < n)     nrm[base]     = 1.0f / sqrtf(fmaxf((float)v0, 1.0f));
  if (base + 1 < n) nrm[base + 1] = 1.0f / sqrtf(fmaxf((float)v1, 1.0f));
  if (base + 2 < n) nrm[base + 2] = 1.0f / sqrtf(fmaxf((float)v2, 1.0f));
  if (base + 3 < n) nrm[base + 3] = 1.0f / sqrtf(fmaxf((float)v3, 1.0f));
  int ts = v0 + v1 + v2 + v3;
  int lane = t & 63, wv = t >> 6;
  int incl = ts;
  #pragma unroll
  for (int off = 1; off < 64; off <<= 1) {
    int o = __shfl_up(incl, off, 64);
    if (lane >= off) incl += o;
  }
  if (lane == 63) wsum[wv] = incl;
  __syncthreads();
  int woff = 0;
  #pragma unroll
  for (int i = 0; i < 4; ++i) if (i < wv) woff += wsum[i];
  int excl = woff + incl - ts;
  int o0 = excl, o1 = o0 + v0, o2 = o1 + v1, o3 = o2 + v2;
  if (base + 3 < n) {
    *(int4*)(rp + base) = make_int4(o0, o1, o2, o3);
  } else if (base < n) {
    rp[base] = o0;
    if (base + 1 < n) rp[base + 1] = o1;
    if (base + 2 < n) rp[base + 2] = o2;
  }
  if (t == 255) bsum[blockIdx.x] = woff + incl;  // block total
}

// exclusive scan of <=256 block sums; writes grand total to rp[n]
__global__ void scan2_kernel(int* __restrict__ bsum, int nb, int* __restrict__ rp_end) {
  __shared__ int s[256];
  int t = threadIdx.x;
  int v = (t < nb) ? bsum[t] : 0;
  s[t] = v;
  __syncthreads();
  int val = v;
  for (int off = 1; off < 256; off <<= 1) {
    int add = (t >= off) ? s[t - off] : 0;
    __syncthreads();
    val += add;
    s[t] = val;
    __syncthreads();
  }
  if (t < nb) bsum[t] = val - v;  // exclusive
  if (t == 255) *rp_end = val;    // total
}

__global__ void scan3_kernel(int* __restrict__ rp, const int* __restrict__ bsum, int n) {
  int i = blockIdx.x * 256 + threadIdx.x;
  if (i < n) rp[i] += bsum[i >> 10];
}

__global__ void scatter_kernel(const int* __restrict__ src, const int* __restrict__ dst,
                               const int* __restrict__ rp, int* __restrict__ cur,
                               int* __restrict__ col, int e) {
  int i = blockIdx.x * 256 + threadIdx.x;
  if (i < e) {
    int d = dst[i];
    int p = rp[d] + atomicAdd(&cur[d], 1);
    col[p] = src[i];
  }
}

// ---------------- protein GNN: feature-chunked hop ----------------
// g = nrm.*h stored fp16 as packed chunk arrays: FULL chunks of 16 feats
// (stride 16, 32B rows, one 64B line per row) + packed tail of TW=DIN%16
// feats (stride TW). Each chunk is ~3.2MB -> per-XCD-L2-resident during its
// gather pass. One kernel runs all passes: pass = blockIdx.x / nbn; blocks
// dispatch ~in-order so one chunk is hot at a time.

__device__ __forceinline__ size_t slot_addr(int slot, int v, int n, int FULL, int TW) {
  if (slot < FULL * 16)
    return ((size_t)(slot >> 4) * n + v) * 16 + (slot & 15);
  return (size_t)FULL * n * 16 + (size_t)v * TW + (slot - FULL * 16);
}

// grid = NPASS*nbn blocks, 256 threads (4 waves x 4 nodes each)
__global__ void gather_all_kernel(const __half* __restrict__ g, const int* __restrict__ rp,
                                  const int* __restrict__ col, __half* __restrict__ s,
                                  int n, int nbn, int FULL, int TW) {
  int pass = blockIdx.x / nbn;
  int bid = blockIdx.x - pass * nbn;
  int lane = threadIdx.x & 63, wv = threadIdx.x >> 6;
  int grp = lane >> 3, f2 = lane & 7;
  int v0 = bid * 16 + wv * 4;
  bool tail = (pass >= FULL);
  const __half* gc = g + (size_t)pass * n * 16;       // full-chunk base
  __half* sc = s + (size_t)pass * n * 16;
  const __half* gt = g + (size_t)FULL * n * 16;       // tail base
  __half* st = s + (size_t)FULL * n * 16;
  for (int t = 0; t < 4; ++t) {
    int v = v0 + t;
    if (v >= n) return;
    int beg = rp[v], end = rp[v + 1];
    float ax = 0.f, ay = 0.f;
    for (int base = beg; base < end; base += 64) {
      int m = end - base; if (m > 64) m = 64;
      int myc = (lane < m) ? col[base + lane] : 0;
      int j = grp;
      if (!tail) {
        for (; j + 8 < m; j += 16) {
          int s0 = __shfl(myc, j, 64);
          int s1 = __shfl(myc, j + 8, 64);
          __half2 h0 = *(const __half2*)(gc + (size_t)s0 * 16 + f2 * 2);
          __half2 h1 = *(const __half2*)(gc + (size_t)s1 * 16 + f2 * 2);
          ax += __low2float(h0) + __low2float(h1);
          ay += __high2float(h0) + __high2float(h1);
        }
        if (j < m) {
          int s0 = __shfl(myc, j, 64);
          __half2 h0 = *(const __half2*)(gc + (size_t)s0 * 16 + f2 * 2);
          ax += __low2float(h0);
          ay += __high2float(h0);
        }
      } else {
        // packed tail rows (TW halves, 2B loads: rows may be 2B-aligned)
        for (; j < m; j += 8) {
          int s0 = __shfl(myc, j, 64);
          const __half* r = gt + (size_t)s0 * TW;
          if (f2 * 2 < TW)     ax += __half2float(r[f2 * 2]);
          if (f2 * 2 + 1 < TW) ay += __half2float(r[f2 * 2 + 1]);
        }
      }
    }
    ax += __shfl_xor(ax, 8, 64);  ay += __shfl_xor(ay, 8, 64);
    ax += __shfl_xor(ax, 16, 64); ay += __shfl_xor(ay, 16, 64);
    ax += __shfl_xor(ax, 32, 64); ay += __shfl_xor(ay, 32, 64);
    if (lane < 8) {
      if (!tail) {
        *(__half2*)(sc + (size_t)v * 16 + lane * 2) = __floats2half2_rn(ax, ay);
      } else {
        if (lane * 2 < TW)     st[(size_t)v * TW + lane * 2]     = __float2half(ax);
        if (lane * 2 + 1 < TW) st[(size_t)v * TW + lane * 2 + 1] = __float2half(ay);
      }
    }
  }
}

// MODE: 0 = init (read x fp32, h=x, g=x*nrm, y=b+x@W0)
//       1 = mid  (read s, h=nrm*s, g=nrm*h, y+=h@Wk)
//       2 = final(read s, h=nrm*s, y+=h@W4 -> relu+l2norm -> X)
template<int DIN, int DOUT, int MODE>
__global__ void finalize_kernel(const float* __restrict__ xin, const __half* __restrict__ s,
                                const float* __restrict__ nrm, const float* __restrict__ W,
                                const float* __restrict__ bias, float* __restrict__ y,
                                __half* __restrict__ g, float* __restrict__ X,
                                int k, int n) {
  constexpr int FULL = DIN / 16;
  constexpr int TW = DIN % 16;
  int lane = threadIdx.x & 63;
  int v = blockIdx.x * 4 + (threadIdx.x >> 6);
  if (v >= n) return;
  float nm = nrm[v];
  float hA = 0.f, hB = 0.f;
  if (MODE == 0) {
    const float* xr = xin + (size_t)v * DIN;
    if (lane < DIN) hA = xr[lane];
    if (DIN > 64) { if (lane + 64 < DIN) hB = xr[lane + 64]; }
  } else {
    if (lane < DIN) hA = __half2float(s[slot_addr(lane, v, n, FULL, TW)]) * nm;
    if (DIN > 64) {
      if (lane + 64 < DIN) hB = __half2float(s[slot_addr(lane + 64, v, n, FULL, TW)]) * nm;
    }
  }
  if (MODE != 2) {
    if (lane < DIN) g[slot_addr(lane, v, n, FULL, TW)] = __float2half(hA * nm);
    if (DIN > 64) {
      if (lane + 64 < DIN) g[slot_addr(lane + 64, v, n, FULL, TW)] = __float2half(hB * nm);
    }
  }
  int cl = (lane < DOUT) ? lane : 0;
  float acc = (MODE == 0) ? bias[cl] : y[(size_t)v * DOUT + cl];
  const float* Wk = W + (size_t)k * DIN * DOUT + cl;
  #pragma unroll
  for (int f = 0; f < DIN; ++f) {
    float hf = (f < 64) ? __shfl(hA, f, 64) : __shfl(hB, f - 64, 64);
    acc += hf * Wk[(size_t)f * DOUT];
  }
  if (MODE == 2) {
    float val = (lane < DOUT) ? fmaxf(acc, 0.f) : 0.f;
    float ss2 = val * val;
    #pragma unroll
    for (int off = 32; off > 0; off >>= 1) ss2 += __shfl_xor(ss2, off, 64);
    float sc = 1.f / fmaxf(sqrtf(ss2), 1e-12f);
    if (lane < DOUT) X[(size_t)v * DOUT + lane] = val * sc;
  } else {
    if (lane < DOUT) y[(size_t)v * DOUT + lane] = acc;
  }
}

// ---------------- ligand GNN: small-n fused hop (g is L2-resident) --------

template<int DIN, int GS, int DOUT>
__global__ void init_gemm_kernel(const float* __restrict__ x, const float* __restrict__ nrm,
                                 const float* __restrict__ W, const float* __restrict__ bias,
                                 __half* __restrict__ gout, float* __restrict__ y, int n) {
  int lane = threadIdx.x & 63;
  int v = blockIdx.x * 4 + (threadIdx.x >> 6);
  if (v >= n) return;
  float nm = nrm[v];
  const float* xr = x + (size_t)v * DIN;
  float hA = (lane < DIN) ? xr[lane] : 0.f;
  float hB = 0.f;
  if constexpr (DIN > 64) { if (lane + 64 < DIN) hB = xr[lane + 64]; }
  __half* go = gout + (size_t)v * GS;
  if (lane < DIN) go[lane] = __float2half(hA * nm);
  if constexpr (DIN > 64) { if (lane + 64 < DIN) go[lane + 64] = __float2half(hB * nm); }
  int cl = (lane < DOUT) ? lane : 0;
  float acc = bias[cl];
  const float* Wk = W + cl;
  #pragma unroll
  for (int f = 0; f < DIN; ++f) {
    float hf = (f < 64) ? __shfl(hA, f, 64) : __shfl(hB, f - 64, 64);
    acc += hf * Wk[(size_t)f * DOUT];
  }
  if (lane < DOUT) y[(size_t)v * DOUT + lane] = acc;
}

template<int DIN, int GS, int DOUT, bool WRITEG, bool FINAL>
__global__ void fused_hop_kernel(const __half* __restrict__ gin, const int* __restrict__ rp,
                                 const int* __restrict__ col, const float* __restrict__ nrm,
                                 const float* __restrict__ W, __half* __restrict__ gout,
                                 float* __restrict__ y, float* __restrict__ Xout,
                                 int k, int n) {
  int lane = threadIdx.x & 63;
  int v = blockIdx.x * 4 + (threadIdx.x >> 6);
  if (v >= n) return;
  int beg = rp[v], end = rp[v + 1];
  float a0 = 0.f, a1 = 0.f;
  for (int base = beg; base < end; base += 64) {
    int m = end - base; if (m > 64) m = 64;
    int myc = (lane < m) ? col[base + lane] : 0;
    int j = 0;
    for (; j + 8 <= m; j += 8) {
      int ss[8];
      float t0[8], t1[8];
      #pragma unroll
      for (int u = 0; u < 8; ++u) ss[u] = __shfl(myc, j + u, 64);
      #pragma unroll
      for (int u = 0; u < 8; ++u) {
        const __half* r = gin + (size_t)ss[u] * GS;
        t0[u] = (lane < DIN) ? __half2float(r[lane]) : 0.f;
        if constexpr (DIN > 64) t1[u] = (lane + 64 < DIN) ? __half2float(r[lane + 64]) : 0.f;
      }
      #pragma unroll
      for (int u = 0; u < 8; ++u) {
        a0 += t0[u];
        if constexpr (DIN > 64) a1 += t1[u];
      }
    }
    for (; j < m; ++j) {
      int s = __shfl(myc, j, 64);
      const __half* r = gin + (size_t)s * GS;
      if (lane < DIN) a0 += __half2float(r[lane]);
      if constexpr (DIN > 64) { if (lane + 64 < DIN) a1 += __half2float(r[lane + 64]); }
    }
  }
  float nm = nrm[v];
  float hA = a0 * nm, hB = a1 * nm;
  if (WRITEG) {
    __half* go = gout + (size_t)v * GS;
    if (lane < DIN) go[lane] = __float2half(hA * nm);
    if constexpr (DIN > 64) { if (lane + 64 < DIN) go[lane + 64] = __float2half(hB * nm); }
  }
  int cl = (lane < DOUT) ? lane : 0;
  float acc = 0.f;
  if (lane < DOUT) acc = y[(size_t)v * DOUT + lane];
  const float* Wk = W + (size_t)k * DIN * DOUT + cl;
  #pragma unroll
  for (int f = 0; f < DIN; ++f) {
    float hf = (f < 64) ? __shfl(hA, f, 64) : __shfl(hB, f - 64, 64);
    acc += hf * Wk[(size_t)f * DOUT];
  }
  if constexpr (FINAL) {
    float val = (lane < DOUT) ? fmaxf(acc, 0.f) : 0.f;
    float ss2 = val * val;
    #pragma unroll
    for (int off2 = 32; off2 > 0; off2 >>= 1) ss2 += __shfl_xor(ss2, off2, 64);
    float scale = 1.f / fmaxf(sqrtf(ss2), 1e-12f);
    if (lane < DOUT) Xout[(size_t)v * DOUT + lane] = val * scale;
  } else {
    if (lane < DOUT) y[(size_t)v * DOUT + lane] = acc;
  }
}

// hierarchical segment-max (values >= 0 post relu+l2norm; rep zeroed first)
__global__ void segmax_kernel(const float* __restrict__ X, const int* __restrict__ gid,
                              float* __restrict__ rep, int n, int row_off) {
  __shared__ float tab[4][45];
  __shared__ int gids[256];
  int t = threadIdx.x;
  for (int i = t; i < 4 * 45; i += 256) ((float*)tab)[i] = 0.f;
  int v0 = blockIdx.x * 256;
  int vend = v0 + 256; if (vend > n) vend = n;
  int nv = vend - v0;
  if (t < nv) gids[t] = gid[v0 + t];
  __syncthreads();
  int g0 = gids[0];
  int total = nv * 45;
  for (int i = t; i < total; i += 256) {
    int vl = i / 45, j = i - vl * 45;
    float val = X[(size_t)(v0 + vl) * 45 + j];
    int rel = gids[vl] - g0;
    if (rel >= 0 && rel < 4)
      atomicMax((unsigned int*)&tab[rel][j], __float_as_uint(val));
    else
      atomicMax((unsigned int*)&rep[(size_t)(row_off + gids[vl]) * 45 + j], __float_as_uint(val));
  }
  __syncthreads();
  for (int i = t; i < 4 * 45; i += 256) {
    float val = ((float*)tab)[i];
    if (val > 0.f) {
      int rel = i / 45, j = i - rel * 45;
      atomicMax((unsigned int*)&rep[(size_t)(row_off + g0 + rel) * 45 + j], __float_as_uint(val));
    }
  }
}

// ---------------- attention ----------------

__global__ void qkv_kernel(const float* __restrict__ rep, const float* __restrict__ w,
                           const float* __restrict__ b, float* __restrict__ qkv) {
  int i = blockIdx.x;      // 0..129
  int t = threadIdx.x;     // 256
  __shared__ float sr[45];
  if (t < 45) sr[t] = (i < 65) ? rep[(size_t)i * 45 + t] : 0.f;
  __syncthreads();
  if (t < 135) {
    float acc = b[t];
    #pragma unroll 5
    for (int d = 0; d < 45; ++d) acc += sr[d] * w[d * 135 + t];
    qkv[(size_t)i * 135 + t] = acc;
  }
}

__global__ void attn_kernel(const float* __restrict__ qkv, const float* __restrict__ proj_w,
                            const float* __restrict__ proj_b, float* __restrict__ ctx) {
  int i = blockIdx.x;     // query row
  int t = threadIdx.x;    // 256
  __shared__ float q[45];
  __shared__ float p[130];
  __shared__ float red[256];
  __shared__ float ao[45];
  if (t < 45) q[t] = qkv[(size_t)i * 135 + t];
  __syncthreads();
  float s = -1e30f;
  if (t < 130) {
    int j = t;
    float dot = 0.f;
    #pragma unroll 5
    for (int d = 0; d < 45; ++d) dot += q[d] * qkv[(size_t)j * 135 + 45 + d];
    dot *= 0.14907119849998599f;  // 45^-0.5
    bool mz;  // mask == 0 ?
    if (i == 64 && j == 64) mz = true;
    else if (i == 64 || j == 64) mz = false;
    else mz = !(i == j && i < 65);
    s = mz ? -1e9f : dot;
  }
  red[t] = s;
  __syncthreads();
  #pragma unroll
  for (int off = 128; off > 0; off >>= 1) {
    if (t < off) red[t] = fmaxf(red[t], red[t + off]);
    __syncthreads();
  }
  float mx = red[0];
  __syncthreads();
  float e = (t < 130) ? expf(s - mx) : 0.f;
  red[t] = e;
  __syncthreads();
  #pragma unroll
  for (int off = 128; off > 0; off >>= 1) {
    if (t < off) red[t] += red[t + off];
    __syncthreads();
  }
  float denom = red[0];
  __syncthreads();
  if (t < 130) p[t] = e / denom;
  __syncthreads();
  if (t < 45) {
    float acc = 0.f;
    for (int j = 0; j < 130; ++j) acc += p[j] * qkv[(size_t)j * 135 + 90 + t];
    ao[t] = acc;
  }
  __syncthreads();
  if (t < 45) {
    float pr = proj_b[t];
    #pragma unroll 5
    for (int e2 = 0; e2 < 45; ++e2) pr += ao[e2] * proj_w[e2 * 45 + t];
    ctx[(size_t)i * 45 + t] = pr;
  }
}

// ---------------- head MLP ----------------

__global__ void bias_init_kernel(const float* __restrict__ b, float* __restrict__ out, int n) {
  int i = blockIdx.x * 256 + threadIdx.x;
  if (i < n) out[i] = b[i];
}

template<bool RELU_IN>
__global__ void fc_splitk_kernel(const float* __restrict__ x, const float* __restrict__ W,
                                 float* __restrict__ out, int nin, int nout, int kchunk) {
  __shared__ float xs[1024];
  int k0 = blockIdx.y * kchunk;
  int k1 = k0 + kchunk; if (k1 > nin) k1 = nin;
  int len = k1 - k0;
  for (int i = threadIdx.x; i < len; i += blockDim.x) {
    float v = x[k0 + i];
    xs[i] = RELU_IN ? fmaxf(v, 0.f) : v;
  }
  __syncthreads();
  int j = blockIdx.x * blockDim.x + threadIdx.x;
  if (j < nout) {
    float acc = 0.f;
    const float* Wp = W + (size_t)k0 * nout + j;
    for (int i = 0; i < len; ++i) acc += xs[i] * Wp[(size_t)i * nout];
    atomicAdd(&out[j], acc);
  }
}

__global__ void final_fc_kernel(const float* __restrict__ x, const float* __restrict__ W,
                                const float* __restrict__ b, float* __restrict__ out) {
  __shared__ float red[512];
  int t = threadIdx.x;
  float acc = 0.f;
  if (t < 500) acc = fmaxf(x[t], 0.f) * W[t];
  red[t] = acc;
  __syncthreads();
  #pragma unroll
  for (int off = 256; off > 0; off >>= 1) {
    if (t < off) red[t] += red[t + off];
    __syncthreads();
  }
  if (t == 0) {
    float z = red[0] + b[0];
    out[0] = 1.f / (1.f + expf(-z));
  }
}

// ---------------- host-side orchestration ----------------

struct Bufs {
  __half *gch, *sch;     // chunked g / s (protein path)
  __half *ligA, *ligB;   // ligand ping/pong
  float *X, *Y, *nrm;
  int *cnt, *cur, *rp, *col, *bsum;
};

template<int DIN, int DOUT>
void run_layer_prot(const float* xin, const Bufs& g, const float* W, const float* b,
                    int n, hipStream_t st) {
  constexpr int FULL = DIN / 16;
  constexpr int TW = DIN % 16;
  constexpr int NPASS = FULL + (TW ? 1 : 0);
  int nbn = (n + 15) / 16;
  int nb4 = (n + 3) / 4;
  finalize_kernel<DIN, DOUT, 0><<<nb4, 256, 0, st>>>(xin, g.sch, g.nrm, W, b, g.Y, g.gch, g.X, 0, n);
  for (int k = 1; k <= 4; ++k) {
    gather_all_kernel<<<NPASS * nbn, 256, 0, st>>>(g.gch, g.rp, g.col, g.sch, n, nbn, FULL, TW);
    if (k < 4)
      finalize_kernel<DIN, DOUT, 1><<<nb4, 256, 0, st>>>(xin, g.sch, g.nrm, W, b, g.Y, g.gch, g.X, k, n);
    else
      finalize_kernel<DIN, DOUT, 2><<<nb4, 256, 0, st>>>(xin, g.sch, g.nrm, W, b, g.Y, g.gch, g.X, 4, n);
  }
}

template<int DIN, int GS, int DOUT>
void run_layer_lig(const float* xin, const Bufs& g, const float* W, const float* b,
                   int n, hipStream_t st) {
  int nb = (n + 3) / 4;
  init_gemm_kernel<DIN, GS, DOUT><<<nb, 256, 0, st>>>(xin, g.nrm, W, b, g.ligA, g.Y, n);
  const __half* gin = g.ligA;
  __half* gout = g.ligB;
  for (int k = 1; k <= 4; ++k) {
    if (k < 4)
      fused_hop_kernel<DIN, GS, DOUT, true, false><<<nb, 256, 0, st>>>(gin, g.rp, g.col, g.nrm, W, gout, g.Y, g.X, k, n);
    else
      fused_hop_kernel<DIN, GS, DOUT, false, true><<<nb, 256, 0, st>>>(gin, g.rp, g.col, g.nrm, W, gout, g.Y, g.X, 4, n);
    __half* t = (__half*)gin; gin = gout; gout = t;
  }
}

void build_csr(const int* src, const int* dst, const Bufs& g, int n, int e, hipStream_t st) {
  hipMemsetAsync(g.cnt, 0, (size_t)n * 4, st);
  hipMemsetAsync(g.cur, 0, (size_t)n * 4, st);
  hist_kernel<<<(e + 255) / 256, 256, 0, st>>>(dst, g.cnt, e);
  int nb1 = (n + 1023) / 1024;
  scan1_kernel<<<nb1, 256, 0, st>>>(g.cnt, g.rp, g.bsum, g.nrm, n);
  scan2_kernel<<<1, 256, 0, st>>>(g.bsum, nb1, g.rp + n);
  scan3_kernel<<<(n + 255) / 256, 256, 0, st>>>(g.rp, g.bsum, n);
  scatter_kernel<<<(e + 255) / 256, 256, 0, st>>>(src, dst, g.rp, g.cur, g.col, e);
}

} // namespace

extern "C" void kernel_launch(void* const* d_in, const int* in_sizes, int n_in,
                              void* d_out, int out_size, void* d_ws, size_t ws_size,
                              hipStream_t stream) {
  (void)in_sizes; (void)n_in; (void)out_size;

  const float* prot_x = (const float*)d_in[0];
  const float* lig_x  = (const float*)d_in[1];
  const float* pW[3] = {(const float*)d_in[2], (const float*)d_in[4], (const float*)d_in[6]};
  const float* pB[3] = {(const float*)d_in[3], (const float*)d_in[5], (const float*)d_in[7]};
  const float* lW[4] = {(const float*)d_in[8], (const float*)d_in[10], (const float*)d_in[12], (const float*)d_in[14]};
  const float* lB[4] = {(const float*)d_in[9], (const float*)d_in[11], (const float*)d_in[13], (const float*)d_in[15]};
  const float* qkv_w = (const float*)d_in[16];
  const float* qkv_b = (const float*)d_in[17];
  const float* proj_w = (const float*)d_in[18];
  const float* proj_b = (const float*)d_in[19];
  const float* h0_w = (const float*)d_in[20];
  const float* h0_b = (const float*)d_in[21];
  const float* h1_w = (const float*)d_in[22];
  const float* h1_b = (const float*)d_in[23];
  const float* h2_w = (const float*)d_in[24];
  const float* h2_b = (const float*)d_in[25];
  const float* fc_w = (const float*)d_in[26];
  const float* fc_b = (const float*)d_in[27];
  const int* prot_src = (const int*)d_in[28];
  const int* prot_dst = (const int*)d_in[29];
  const int* prot_gid = (const int*)d_in[30];
  const int* lig_src  = (const int*)d_in[31];
  const int* lig_dst  = (const int*)d_in[32];
  const int* lig_gid  = (const int*)d_in[33];

  // workspace carve-up
  char* w = (char*)d_ws;
  size_t off = 0;
  auto alloc = [&](size_t bytes) -> void* {
    void* p = w + off;
    off += (bytes + 255) & ~(size_t)255;
    return p;
  };
  __half* gch  = (__half*)alloc((size_t)NPROT * 80 * 2);  // up to 5 chunks of 16
  __half* sch  = (__half*)alloc((size_t)NPROT * 80 * 2);
  __half* ligA = (__half*)alloc((size_t)NLIG * 96 * 2);
  __half* ligB = (__half*)alloc((size_t)NLIG * 96 * 2);
  float* X   = (float*)alloc((size_t)NPROT * 50 * 4);
  float* Y   = (float*)alloc((size_t)NPROT * 50 * 4);
  float* nrm = (float*)alloc((size_t)NPROT * 4);
  int* cnt   = (int*)alloc((size_t)NPROT * 4);
  int* cur   = (int*)alloc((size_t)NPROT * 4);
  int* rp    = (int*)alloc(((size_t)NPROT + 1) * 4);
  int* colb  = (int*)alloc((size_t)EPROT * 4);
  int* bsum  = (int*)alloc((size_t)256 * 4);
  float* rep = (float*)alloc((size_t)65 * 45 * 4);
  float* qkvb = (float*)alloc((size_t)130 * 135 * 4);
  float* ctx  = (float*)alloc((size_t)5850 * 4);
  float* hb0  = (float*)alloc((size_t)2000 * 4);
  float* hb1  = (float*)alloc((size_t)1000 * 4);
  float* hb2  = (float*)alloc((size_t)500 * 4);
  if (off > ws_size) return;  // workspace too small: fail loudly via validation

  hipMemsetAsync(rep, 0, (size_t)65 * 45 * 4, stream);

  Bufs g{gch, sch, ligA, ligB, X, Y, nrm, cnt, cur, rp, colb, bsum};

  // ---- protein GNN (feature-chunked, L2-resident gather passes) ----
  build_csr(prot_src, prot_dst, g, NPROT, EPROT, stream);
  run_layer_prot<74, 50>(prot_x, g, pW[0], pB[0], NPROT, stream);
  run_layer_prot<50, 45>(g.X, g, pW[1], pB[1], NPROT, stream);
  run_layer_prot<45, 45>(g.X, g, pW[2], pB[2], NPROT, stream);
  segmax_kernel<<<(NPROT + 255) / 256, 256, 0, stream>>>(g.X, prot_gid, rep, NPROT, 1);

  // ---- ligand GNN (small; fused path) ----
  build_csr(lig_src, lig_dst, g, NLIG, ELIG, stream);
  run_layer_lig<74, 96, 50>(lig_x, g, lW[0], lB[0], NLIG, stream);
  run_layer_lig<50, 64, 45>(g.X, g, lW[1], lB[1], NLIG, stream);
  run_layer_lig<45, 64, 45>(g.X, g, lW[2], lB[2], NLIG, stream);
  run_layer_lig<45, 64, 45>(g.X, g, lW[3], lB[3], NLIG, stream);
  segmax_kernel<<<(NLIG + 255) / 256, 256, 0, stream>>>(g.X, lig_gid, rep, NLIG, 0);

  // ---- attention ----
  qkv_kernel<<<130, 256, 0, stream>>>(rep, qkv_w, qkv_b, qkvb);
  attn_kernel<<<130, 256, 0, stream>>>(qkvb, proj_w, proj_b, ctx);

  // ---- head MLP ----
  bias_init_kernel<<<8, 256, 0, stream>>>(h0_b, hb0, 2000);
  fc_splitk_kernel<false><<<dim3(8, 8), 256, 0, stream>>>(ctx, h0_w, hb0, 5850, 2000, 732);
  bias_init_kernel<<<4, 256, 0, stream>>>(h1_b, hb1, 1000);
  fc_splitk_kernel<true><<<dim3(4, 4), 256, 0, stream>>>(hb0, h1_w, hb1, 2000, 1000, 500);
  bias_init_kernel<<<2, 256, 0, stream>>>(h2_b, hb2, 500);
  fc_splitk_kernel<true><<<dim3(2, 2), 256, 0, stream>>>(hb1, h2_w, hb2, 1000, 500, 500);
  final_fc_kernel<<<1, 512, 0, stream>>>(hb2, fc_w, fc_b, (float*)d_out);
}

// Round 7
// 2177.807 us; speedup vs baseline: 1.2701x; 1.2701x over previous
//
#include <hip/hip_runtime.h>
#include <hip/hip_fp16.h>
#include <cstddef>
#include <cstdint>

namespace {

constexpr int NPROT = 100000;
constexpr int EPROT = 1600000;
constexpr int NLIG  = 5000;
constexpr int ELIG  = 80000;

// ---------------- CSR construction ----------------

__global__ void hist_kernel(const int* __restrict__ dst, int* __restrict__ cnt, int e) {
  int i = blockIdx.x * 256 + threadIdx.x;
  if (i < e) atomicAdd(&cnt[dst[i]], 1);
}

// per-block (1024 elems) exclusive scan; also computes nrm = max(deg,1)^-0.5
__global__ void scan1_kernel(const int* __restrict__ cnt, int* __restrict__ rp,
                             int* __restrict__ bsum, float* __restrict__ nrm, int n) {
  __shared__ int wsum[4];
  int t = threadIdx.x;
  int base = blockIdx.x * 1024 + t * 4;
  int v0 = 0, v1 = 0, v2 = 0, v3 = 0;
  if (base + 3 < n) {
    int4 val = *(const int4*)(cnt + base);
    v0 = val.x; v1 = val.y; v2 = val.z; v3 = val.w;
  } else if (base < n) {
    v0 = cnt[base];
    if (base + 1 < n) v1 = cnt[base + 1];
    if (base + 2 < n) v2 = cnt[base + 2];
  }
  if (base < n)     nrm[base]     = 1.0f / sqrtf(fmaxf((float)v0, 1.0f));
  if (base + 1 < n) nrm[base + 1] = 1.0f / sqrtf(fmaxf((float)v1, 1.0f));
  if (base + 2 < n) nrm[base + 2] = 1.0f / sqrtf(fmaxf((float)v2, 1.0f));
  if (base + 3 < n) nrm[base + 3] = 1.0f / sqrtf(fmaxf((float)v3, 1.0f));
  int ts = v0 + v1 + v2 + v3;
  int lane = t & 63, wv = t >> 6;
  int incl = ts;
  #pragma unroll
  for (int off = 1; off < 64; off <<= 1) {
    int o = __shfl_up(incl, off, 64);
    if (lane >= off) incl += o;
  }
  if (lane == 63) wsum[wv] = incl;
  __syncthreads();
  int woff = 0;
  #pragma unroll
  for (int i = 0; i < 4; ++i) if (i < wv) woff += wsum[i];
  int excl = woff + incl - ts;
  int o0 = excl, o1 = o0 + v0, o2 = o1 + v1, o3 = o2 + v2;
  if (base + 3 < n) {
    *(int4*)(rp + base) = make_int4(o0, o1, o2, o3);
  } else if (base < n) {
    rp[base] = o0;
    if (base + 1 < n) rp[base + 1] = o1;
    if (base + 2 < n) rp[base + 2] = o2;
  }
  if (t == 255) bsum[blockIdx.x] = woff + incl;  // block total
}

// exclusive scan of <=256 block sums; writes grand total to rp[n]
__global__ void scan2_kernel(int* __restrict__ bsum, int nb, int* __restrict__ rp_end) {
  __shared__ int s[256];
  int t = threadIdx.x;
  int v = (t < nb) ? bsum[t] : 0;
  s[t] = v;
  __syncthreads();
  int val = v;
  for (int off = 1; off < 256; off <<= 1) {
    int add = (t >= off) ? s[t - off] : 0;
    __syncthreads();
    val += add;
    s[t] = val;
    __syncthreads();
  }
  if (t < nb) bsum[t] = val - v;  // exclusive
  if (t == 255) *rp_end = val;    // total
}

__global__ void scan3_kernel(int* __restrict__ rp, const int* __restrict__ bsum, int n) {
  int i = blockIdx.x * 256 + threadIdx.x;
  if (i < n) rp[i] += bsum[i >> 10];
}

__global__ void scatter_kernel(const int* __restrict__ src, const int* __restrict__ dst,
                               const int* __restrict__ rp, int* __restrict__ cur,
                               int* __restrict__ col, int e) {
  int i = blockIdx.x * 256 + threadIdx.x;
  if (i < e) {
    int d = dst[i];
    int p = rp[d] + atomicAdd(&cur[d], 1);
    col[p] = src[i];
  }
}

// ---------------- protein GNN ----------------
// g_k = nrm.*h_k stored fp16 in 16-feat chunks padded to PD=ceil(DIN/16)*16
// (pads are zero and stay zero through hops). Chunk c, node v, slot s:
//   addr = (c*n + v)*16 + s   -> 32B rows, one 64B line per 2 rows.
// Each chunk (3.2MB) is per-XCD-L2-resident during its gather pass.
// gather computes g_k = nrm^2 * sum_{src} g_{k-1}[src] directly.
// GEMM kernels recover h_k = g_k / nrm and accumulate y += h_k @ W_k.

// grid = NPASS*nbn (pass-major: one chunk hot at a time); 256 thr = 4 waves.
// Wave = 4 nodes x 16 lanes (2 edge slots x 8 feat-pair lanes); inner loop
// compile-time unrolled 8 deep -> 8 clamped branch-free loads in flight/lane.
__global__ void gather_all_kernel(const __half* __restrict__ gin, const int* __restrict__ rp,
                                  const int* __restrict__ col, const float* __restrict__ nrm,
                                  __half* __restrict__ gout, int n, int nbn) {
  int pass = blockIdx.x / nbn;
  int bid = blockIdx.x - pass * nbn;
  int lane = threadIdx.x & 63, wv = threadIdx.x >> 6;
  int q = lane >> 4, r = lane & 15;
  int e_slot = r >> 3, f2 = r & 7;
  int v = bid * 16 + wv * 4 + q;
  bool vok = (v < n);
  int beg = 0, deg = 0;
  if (vok) { beg = rp[v]; deg = rp[v + 1] - beg; }
  const __half* gc = gin + (size_t)pass * n * 16;
  __half* go = gout + (size_t)pass * n * 16;
  float ax = 0.f, ay = 0.f;
  for (int base = 0; __any(base < deg); base += 16) {
    int ec = (base + r < deg) ? col[beg + base + r] : -1;
    #pragma unroll
    for (int js = 0; js < 16; js += 2) {
      int sl = (q << 4) + js + e_slot;
      int s0 = __shfl(ec, sl, 64);
      int idx = (s0 >= 0) ? s0 : 0;             // clamped: load row 0 when invalid
      float m = (s0 >= 0) ? 1.f : 0.f;
      __half2 h2 = *(const __half2*)(gc + (size_t)idx * 16 + (f2 << 1));
      ax += m * __low2float(h2);
      ay += m * __high2float(h2);
    }
  }
  ax += __shfl_xor(ax, 8, 64);
  ay += __shfl_xor(ay, 8, 64);
  if (vok && e_slot == 0) {
    float nm = nrm[v];
    float nm2 = nm * nm;
    *(__half2*)(go + (size_t)v * 16 + (f2 << 1)) = __floats2half2_rn(ax * nm2, ay * nm2);
  }
}

// MODE: 0 = layer-1 init: read x fp32, write g0 = x*nrm chunks, y = b + x@W0
//       1 = layer init  : read g0 chunks, y = b + (g0/nrm)@W0
//       2 = mid hop     : y += (gk/nrm)@Wk
//       3 = final hop   : y += ..., relu+l2norm; write next-layer g0 chunks
//                         (or X fp32 if LAST)
template<int DIN, int DOUT, int MODE, bool LAST>
__global__ void gemm_kernel(const float* __restrict__ xin, const __half* __restrict__ gk,
                            const float* __restrict__ nrm, const float* __restrict__ W,
                            const float* __restrict__ bias, float* __restrict__ y,
                            __half* __restrict__ gnext, float* __restrict__ Xout,
                            int k, int n) {
  int lane = threadIdx.x & 63;
  int v = blockIdx.x * 4 + (threadIdx.x >> 6);
  if (v >= n) return;
  float nm = nrm[v];
  float rn = 1.f / nm;
  float hA = 0.f, hB = 0.f;
  if (MODE == 0) {
    const float* xr = xin + (size_t)v * DIN;
    if (lane < DIN) hA = xr[lane];
    if (DIN > 64) { if (lane + 64 < DIN) hB = xr[lane + 64]; }
    constexpr int PD = (DIN + 15) & ~15;
    {
      float gv = (lane < DIN) ? hA * nm : 0.f;
      gnext[(((size_t)(lane >> 4) * n + v) << 4) + (lane & 15)] = __float2half(gv);
      if (PD > 64) {
        int l2 = lane + 64;
        if (l2 < PD) {
          float gv2 = (l2 < DIN) ? hB * nm : 0.f;
          gnext[(((size_t)(l2 >> 4) * n + v) << 4) + (l2 & 15)] = __float2half(gv2);
        }
      }
    }
  } else {
    if (lane < DIN)
      hA = __half2float(gk[(((size_t)(lane >> 4) * n + v) << 4) + (lane & 15)]) * rn;
    if (DIN > 64) {
      int l2 = lane + 64;
      if (l2 < DIN)
        hB = __half2float(gk[(((size_t)(l2 >> 4) * n + v) << 4) + (l2 & 15)]) * rn;
    }
  }
  int cl = (lane < DOUT) ? lane : 0;
  float acc = (MODE <= 1) ? bias[cl] : y[(size_t)v * DOUT + cl];
  const float* Wk = W + (size_t)k * DIN * DOUT + cl;
  #pragma unroll
  for (int f = 0; f < DIN; ++f) {
    float hf = (f < 64) ? __shfl(hA, f, 64) : __shfl(hB, f - 64, 64);
    acc += hf * Wk[(size_t)f * DOUT];
  }
  if (MODE == 3) {
    float val = (lane < DOUT) ? fmaxf(acc, 0.f) : 0.f;
    float ss2 = val * val;
    #pragma unroll
    for (int off = 32; off > 0; off >>= 1) ss2 += __shfl_xor(ss2, off, 64);
    float sc = 1.f / fmaxf(sqrtf(ss2), 1e-12f);
    float xv = val * sc;
    if (LAST) {
      if (lane < DOUT) Xout[(size_t)v * DOUT + lane] = xv;
    } else {
      constexpr int PDN = (DOUT + 15) & ~15;   // <= 64
      if (lane < PDN) {
        float gv = (lane < DOUT) ? xv * nm : 0.f;
        gnext[(((size_t)(lane >> 4) * n + v) << 4) + (lane & 15)] = __float2half(gv);
      }
    }
  } else {
    if (lane < DOUT) y[(size_t)v * DOUT + lane] = acc;
  }
}

// ---------------- ligand GNN: small-n fused hop (g is L2-resident) --------

template<int DIN, int GS, int DOUT>
__global__ void init_gemm_kernel(const float* __restrict__ x, const float* __restrict__ nrm,
                                 const float* __restrict__ W, const float* __restrict__ bias,
                                 __half* __restrict__ gout, float* __restrict__ y, int n) {
  int lane = threadIdx.x & 63;
  int v = blockIdx.x * 4 + (threadIdx.x >> 6);
  if (v >= n) return;
  float nm = nrm[v];
  const float* xr = x + (size_t)v * DIN;
  float hA = (lane < DIN) ? xr[lane] : 0.f;
  float hB = 0.f;
  if constexpr (DIN > 64) { if (lane + 64 < DIN) hB = xr[lane + 64]; }
  __half* go = gout + (size_t)v * GS;
  if (lane < DIN) go[lane] = __float2half(hA * nm);
  if constexpr (DIN > 64) { if (lane + 64 < DIN) go[lane + 64] = __float2half(hB * nm); }
  int cl = (lane < DOUT) ? lane : 0;
  float acc = bias[cl];
  const float* Wk = W + cl;
  #pragma unroll
  for (int f = 0; f < DIN; ++f) {
    float hf = (f < 64) ? __shfl(hA, f, 64) : __shfl(hB, f - 64, 64);
    acc += hf * Wk[(size_t)f * DOUT];
  }
  if (lane < DOUT) y[(size_t)v * DOUT + lane] = acc;
}

template<int DIN, int GS, int DOUT, bool WRITEG, bool FINAL>
__global__ void fused_hop_kernel(const __half* __restrict__ gin, const int* __restrict__ rp,
                                 const int* __restrict__ col, const float* __restrict__ nrm,
                                 const float* __restrict__ W, __half* __restrict__ gout,
                                 float* __restrict__ y, float* __restrict__ Xout,
                                 int k, int n) {
  int lane = threadIdx.x & 63;
  int v = blockIdx.x * 4 + (threadIdx.x >> 6);
  if (v >= n) return;
  int beg = rp[v], end = rp[v + 1];
  float a0 = 0.f, a1 = 0.f;
  for (int base = beg; base < end; base += 64) {
    int m = end - base; if (m > 64) m = 64;
    int myc = (lane < m) ? col[base + lane] : 0;
    int j = 0;
    for (; j + 8 <= m; j += 8) {
      int ss[8];
      float t0[8], t1[8];
      #pragma unroll
      for (int u = 0; u < 8; ++u) ss[u] = __shfl(myc, j + u, 64);
      #pragma unroll
      for (int u = 0; u < 8; ++u) {
        const __half* rr = gin + (size_t)ss[u] * GS;
        t0[u] = (lane < DIN) ? __half2float(rr[lane]) : 0.f;
        if constexpr (DIN > 64) t1[u] = (lane + 64 < DIN) ? __half2float(rr[lane + 64]) : 0.f;
      }
      #pragma unroll
      for (int u = 0; u < 8; ++u) {
        a0 += t0[u];
        if constexpr (DIN > 64) a1 += t1[u];
      }
    }
    for (; j < m; ++j) {
      int s = __shfl(myc, j, 64);
      const __half* rr = gin + (size_t)s * GS;
      if (lane < DIN) a0 += __half2float(rr[lane]);
      if constexpr (DIN > 64) { if (lane + 64 < DIN) a1 += __half2float(rr[lane + 64]); }
    }
  }
  float nm = nrm[v];
  float hA = a0 * nm, hB = a1 * nm;
  if (WRITEG) {
    __half* go = gout + (size_t)v * GS;
    if (lane < DIN) go[lane] = __float2half(hA * nm);
    if constexpr (DIN > 64) { if (lane + 64 < DIN) go[lane + 64] = __float2half(hB * nm); }
  }
  int cl = (lane < DOUT) ? lane : 0;
  float acc = 0.f;
  if (lane < DOUT) acc = y[(size_t)v * DOUT + lane];
  const float* Wk = W + (size_t)k * DIN * DOUT + cl;
  #pragma unroll
  for (int f = 0; f < DIN; ++f) {
    float hf = (f < 64) ? __shfl(hA, f, 64) : __shfl(hB, f - 64, 64);
    acc += hf * Wk[(size_t)f * DOUT];
  }
  if constexpr (FINAL) {
    float val = (lane < DOUT) ? fmaxf(acc, 0.f) : 0.f;
    float ss2 = val * val;
    #pragma unroll
    for (int off2 = 32; off2 > 0; off2 >>= 1) ss2 += __shfl_xor(ss2, off2, 64);
    float scale = 1.f / fmaxf(sqrtf(ss2), 1e-12f);
    if (lane < DOUT) Xout[(size_t)v * DOUT + lane] = val * scale;
  } else {
    if (lane < DOUT) y[(size_t)v * DOUT + lane] = acc;
  }
}

// hierarchical segment-max (values >= 0 post relu+l2norm; rep zeroed first)
__global__ void segmax_kernel(const float* __restrict__ X, const int* __restrict__ gid,
                              float* __restrict__ rep, int n, int row_off) {
  __shared__ float tab[4][45];
  __shared__ int gids[256];
  int t = threadIdx.x;
  for (int i = t; i < 4 * 45; i += 256) ((float*)tab)[i] = 0.f;
  int v0 = blockIdx.x * 256;
  int vend = v0 + 256; if (vend > n) vend = n;
  int nv = vend - v0;
  if (t < nv) gids[t] = gid[v0 + t];
  __syncthreads();
  int g0 = gids[0];
  int total = nv * 45;
  for (int i = t; i < total; i += 256) {
    int vl = i / 45, j = i - vl * 45;
    float val = X[(size_t)(v0 + vl) * 45 + j];
    int rel = gids[vl] - g0;
    if (rel >= 0 && rel < 4)
      atomicMax((unsigned int*)&tab[rel][j], __float_as_uint(val));
    else
      atomicMax((unsigned int*)&rep[(size_t)(row_off + gids[vl]) * 45 + j], __float_as_uint(val));
  }
  __syncthreads();
  for (int i = t; i < 4 * 45; i += 256) {
    float val = ((float*)tab)[i];
    if (val > 0.f) {
      int rel = i / 45, j = i - rel * 45;
      atomicMax((unsigned int*)&rep[(size_t)(row_off + g0 + rel) * 45 + j], __float_as_uint(val));
    }
  }
}

// ---------------- attention ----------------

__global__ void qkv_kernel(const float* __restrict__ rep, const float* __restrict__ w,
                           const float* __restrict__ b, float* __restrict__ qkv) {
  int i = blockIdx.x;      // 0..129
  int t = threadIdx.x;     // 256
  __shared__ float sr[45];
  if (t < 45) sr[t] = (i < 65) ? rep[(size_t)i * 45 + t] : 0.f;
  __syncthreads();
  if (t < 135) {
    float acc = b[t];
    #pragma unroll 5
    for (int d = 0; d < 45; ++d) acc += sr[d] * w[d * 135 + t];
    qkv[(size_t)i * 135 + t] = acc;
  }
}

__global__ void attn_kernel(const float* __restrict__ qkv, const float* __restrict__ proj_w,
                            const float* __restrict__ proj_b, float* __restrict__ ctx) {
  int i = blockIdx.x;     // query row
  int t = threadIdx.x;    // 256
  __shared__ float q[45];
  __shared__ float p[130];
  __shared__ float red[256];
  __shared__ float ao[45];
  if (t < 45) q[t] = qkv[(size_t)i * 135 + t];
  __syncthreads();
  float s = -1e30f;
  if (t < 130) {
    int j = t;
    float dot = 0.f;
    #pragma unroll 5
    for (int d = 0; d < 45; ++d) dot += q[d] * qkv[(size_t)j * 135 + 45 + d];
    dot *= 0.14907119849998599f;  // 45^-0.5
    bool mz;  // mask == 0 ?
    if (i == 64 && j == 64) mz = true;
    else if (i == 64 || j == 64) mz = false;
    else mz = !(i == j && i < 65);
    s = mz ? -1e9f : dot;
  }
  red[t] = s;
  __syncthreads();
  #pragma unroll
  for (int off = 128; off > 0; off >>= 1) {
    if (t < off) red[t] = fmaxf(red[t], red[t + off]);
    __syncthreads();
  }
  float mx = red[0];
  __syncthreads();
  float e = (t < 130) ? expf(s - mx) : 0.f;
  red[t] = e;
  __syncthreads();
  #pragma unroll
  for (int off = 128; off > 0; off >>= 1) {
    if (t < off) red[t] += red[t + off];
    __syncthreads();
  }
  float denom = red[0];
  __syncthreads();
  if (t < 130) p[t] = e / denom;
  __syncthreads();
  if (t < 45) {
    float acc = 0.f;
    for (int j = 0; j < 130; ++j) acc += p[j] * qkv[(size_t)j * 135 + 90 + t];
    ao[t] = acc;
  }
  __syncthreads();
  if (t < 45) {
    float pr = proj_b[t];
    #pragma unroll 5
    for (int e2 = 0; e2 < 45; ++e2) pr += ao[e2] * proj_w[e2 * 45 + t];
    ctx[(size_t)i * 45 + t] = pr;
  }
}

// ---------------- head MLP ----------------

__global__ void bias_init_kernel(const float* __restrict__ b, float* __restrict__ out, int n) {
  int i = blockIdx.x * 256 + threadIdx.x;
  if (i < n) out[i] = b[i];
}

template<bool RELU_IN>
__global__ void fc_splitk_kernel(const float* __restrict__ x, const float* __restrict__ W,
                                 float* __restrict__ out, int nin, int nout, int kchunk) {
  __shared__ float xs[1024];
  int k0 = blockIdx.y * kchunk;
  int k1 = k0 + kchunk; if (k1 > nin) k1 = nin;
  int len = k1 - k0;
  for (int i = threadIdx.x; i < len; i += blockDim.x) {
    float v = x[k0 + i];
    xs[i] = RELU_IN ? fmaxf(v, 0.f) : v;
  }
  __syncthreads();
  int j = blockIdx.x * blockDim.x + threadIdx.x;
  if (j < nout) {
    float acc = 0.f;
    const float* Wp = W + (size_t)k0 * nout + j;
    for (int i = 0; i < len; ++i) acc += xs[i] * Wp[(size_t)i * nout];
    atomicAdd(&out[j], acc);
  }
}

__global__ void final_fc_kernel(const float* __restrict__ x, const float* __restrict__ W,
                                const float* __restrict__ b, float* __restrict__ out) {
  __shared__ float red[512];
  int t = threadIdx.x;
  float acc = 0.f;
  if (t < 500) acc = fmaxf(x[t], 0.f) * W[t];
  red[t] = acc;
  __syncthreads();
  #pragma unroll
  for (int off = 256; off > 0; off >>= 1) {
    if (t < off) red[t] += red[t + off];
    __syncthreads();
  }
  if (t == 0) {
    float z = red[0] + b[0];
    out[0] = 1.f / (1.f + expf(-z));
  }
}

// ---------------- host-side orchestration ----------------

struct Bufs {
  __half *gA, *gB;       // protein chunk slabs (ping/pong)
  __half *ligA, *ligB;   // ligand ping/pong
  float *X, *Y, *nrm;
  int *cnt, *cur, *rp, *col, *bsum;
};

// returns the slab holding the NEXT layer's g0 (or X written if LAST)
template<int DIN, int DOUT, bool FIRST, bool LAST>
__half* run_layer_prot(const float* xin, __half* s0, __half* s1, const Bufs& g,
                       const float* W, const float* b, int n, hipStream_t st) {
  constexpr int NPASS = (DIN + 15) / 16;
  int nbn = (n + 15) / 16;
  int nb4 = (n + 3) / 4;
  if (FIRST)
    gemm_kernel<DIN, DOUT, 0, false><<<nb4, 256, 0, st>>>(xin, nullptr, g.nrm, W, b, g.Y, s0, nullptr, 0, n);
  else
    gemm_kernel<DIN, DOUT, 1, false><<<nb4, 256, 0, st>>>(nullptr, s0, g.nrm, W, b, g.Y, nullptr, nullptr, 0, n);
  __half* cur = s0; __half* oth = s1;
  for (int k = 1; k <= 4; ++k) {
    gather_all_kernel<<<NPASS * nbn, 256, 0, st>>>(cur, g.rp, g.col, g.nrm, oth, n, nbn);
    if (k < 4) {
      gemm_kernel<DIN, DOUT, 2, false><<<nb4, 256, 0, st>>>(nullptr, oth, g.nrm, W, b, g.Y, nullptr, nullptr, k, n);
      __half* t = cur; cur = oth; oth = t;
    } else {
      gemm_kernel<DIN, DOUT, 3, LAST><<<nb4, 256, 0, st>>>(nullptr, oth, g.nrm, W, b, g.Y, cur, g.X, 4, n);
    }
  }
  return cur;  // next-layer g0 (valid when !LAST)
}

template<int DIN, int GS, int DOUT>
void run_layer_lig(const float* xin, const Bufs& g, const float* W, const float* b,
                   int n, hipStream_t st) {
  int nb = (n + 3) / 4;
  init_gemm_kernel<DIN, GS, DOUT><<<nb, 256, 0, st>>>(xin, g.nrm, W, b, g.ligA, g.Y, n);
  const __half* gin = g.ligA;
  __half* gout = g.ligB;
  for (int k = 1; k <= 4; ++k) {
    if (k < 4)
      fused_hop_kernel<DIN, GS, DOUT, true, false><<<nb, 256, 0, st>>>(gin, g.rp, g.col, g.nrm, W, gout, g.Y, g.X, k, n);
    else
      fused_hop_kernel<DIN, GS, DOUT, false, true><<<nb, 256, 0, st>>>(gin, g.rp, g.col, g.nrm, W, gout, g.Y, g.X, 4, n);
    __half* t = (__half*)gin; gin = gout; gout = t;
  }
}

void build_csr(const int* src, const int* dst, const Bufs& g, int n, int e, hipStream_t st) {
  hipMemsetAsync(g.cnt, 0, (size_t)n * 4, st);
  hipMemsetAsync(g.cur, 0, (size_t)n * 4, st);
  hist_kernel<<<(e + 255) / 256, 256, 0, st>>>(dst, g.cnt, e);
  int nb1 = (n + 1023) / 1024;
  scan1_kernel<<<nb1, 256, 0, st>>>(g.cnt, g.rp, g.bsum, g.nrm, n);
  scan2_kernel<<<1, 256, 0, st>>>(g.bsum, nb1, g.rp + n);
  scan3_kernel<<<(n + 255) / 256, 256, 0, st>>>(g.rp, g.bsum, n);
  scatter_kernel<<<(e + 255) / 256, 256, 0, st>>>(src, dst, g.rp, g.cur, g.col, e);
}

} // namespace

extern "C" void kernel_launch(void* const* d_in, const int* in_sizes, int n_in,
                              void* d_out, int out_size, void* d_ws, size_t ws_size,
                              hipStream_t stream) {
  (void)in_sizes; (void)n_in; (void)out_size;

  const float* prot_x = (const float*)d_in[0];
  const float* lig_x  = (const float*)d_in[1];
  const float* pW[3] = {(const float*)d_in[2], (const float*)d_in[4], (const float*)d_in[6]};
  const float* pB[3] = {(const float*)d_in[3], (const float*)d_in[5], (const float*)d_in[7]};
  const float* lW[4] = {(const float*)d_in[8], (const float*)d_in[10], (const float*)d_in[12], (const float*)d_in[14]};
  const float* lB[4] = {(const float*)d_in[9], (const float*)d_in[11], (const float*)d_in[13], (const float*)d_in[15]};
  const float* qkv_w = (const float*)d_in[16];
  const float* qkv_b = (const float*)d_in[17];
  const float* proj_w = (const float*)d_in[18];
  const float* proj_b = (const float*)d_in[19];
  const float* h0_w = (const float*)d_in[20];
  const float* h0_b = (const float*)d_in[21];
  const float* h1_w = (const float*)d_in[22];
  const float* h1_b = (const float*)d_in[23];
  const float* h2_w = (const float*)d_in[24];
  const float* h2_b = (const float*)d_in[25];
  const float* fc_w = (const float*)d_in[26];
  const float* fc_b = (const float*)d_in[27];
  const int* prot_src = (const int*)d_in[28];
  const int* prot_dst = (const int*)d_in[29];
  const int* prot_gid = (const int*)d_in[30];
  const int* lig_src  = (const int*)d_in[31];
  const int* lig_dst  = (const int*)d_in[32];
  const int* lig_gid  = (const int*)d_in[33];

  // workspace carve-up
  char* w = (char*)d_ws;
  size_t off = 0;
  auto alloc = [&](size_t bytes) -> void* {
    void* p = w + off;
    off += (bytes + 255) & ~(size_t)255;
    return p;
  };
  __half* gA   = (__half*)alloc((size_t)NPROT * 80 * 2);  // 5 chunks max
  __half* gB   = (__half*)alloc((size_t)NPROT * 80 * 2);
  __half* ligA = (__half*)alloc((size_t)NLIG * 96 * 2);
  __half* ligB = (__half*)alloc((size_t)NLIG * 96 * 2);
  float* X   = (float*)alloc((size_t)NPROT * 50 * 4);
  float* Y   = (float*)alloc((size_t)NPROT * 50 * 4);
  float* nrm = (float*)alloc((size_t)NPROT * 4);
  int* cnt   = (int*)alloc((size_t)NPROT * 4);
  int* cur   = (int*)alloc((size_t)NPROT * 4);
  int* rp    = (int*)alloc(((size_t)NPROT + 1) * 4);
  int* colb  = (int*)alloc((size_t)EPROT * 4);
  int* bsum  = (int*)alloc((size_t)256 * 4);
  float* rep = (float*)alloc((size_t)65 * 45 * 4);
  float* qkvb = (float*)alloc((size_t)130 * 135 * 4);
  float* ctx  = (float*)alloc((size_t)5850 * 4);
  float* hb0  = (float*)alloc((size_t)2000 * 4);
  float* hb1  = (float*)alloc((size_t)1000 * 4);
  float* hb2  = (float*)alloc((size_t)500 * 4);
  if (off > ws_size) return;  // workspace too small: fail loudly via validation

  hipMemsetAsync(rep, 0, (size_t)65 * 45 * 4, stream);

  Bufs g{gA, gB, ligA, ligB, X, Y, nrm, cnt, cur, rp, colb, bsum};

  // ---- protein GNN (chunked L2-resident gathers; g0 handoff between layers)
  build_csr(prot_src, prot_dst, g, NPROT, EPROT, stream);
  __half* g1 = run_layer_prot<74, 50, true,  false>(prot_x, gA, gB, g, pW[0], pB[0], NPROT, stream);
  __half* o1 = (g1 == gA) ? gB : gA;
  __half* g2 = run_layer_prot<50, 45, false, false>(nullptr, g1, o1, g, pW[1], pB[1], NPROT, stream);
  __half* o2 = (g2 == gA) ? gB : gA;
  run_layer_prot<45, 45, false, true>(nullptr, g2, o2, g, pW[2], pB[2], NPROT, stream);
  segmax_kernel<<<(NPROT + 255) / 256, 256, 0, stream>>>(g.X, prot_gid, rep, NPROT, 1);

  // ---- ligand GNN (small; fused path) ----
  build_csr(lig_src, lig_dst, g, NLIG, ELIG, stream);
  run_layer_lig<74, 96, 50>(lig_x, g, lW[0], lB[0], NLIG, stream);
  run_layer_lig<50, 64, 45>(g.X, g, lW[1], lB[1], NLIG, stream);
  run_layer_lig<45, 64, 45>(g.X, g, lW[2], lB[2], NLIG, stream);
  run_layer_lig<45, 64, 45>(g.X, g, lW[3], lB[3], NLIG, stream);
  segmax_kernel<<<(NLIG + 255) / 256, 256, 0, stream>>>(g.X, lig_gid, rep, NLIG, 0);

  // ---- attention ----
  qkv_kernel<<<130, 256, 0, stream>>>(rep, qkv_w, qkv_b, qkvb);
  attn_kernel<<<130, 256, 0, stream>>>(qkvb, proj_w, proj_b, ctx);

  // ---- head MLP ----
  bias_init_kernel<<<8, 256, 0, stream>>>(h0_b, hb0, 2000);
  fc_splitk_kernel<false><<<dim3(8, 8), 256, 0, stream>>>(ctx, h0_w, hb0, 5850, 2000, 732);
  bias_init_kernel<<<4, 256, 0, stream>>>(h1_b, hb1, 1000);
  fc_splitk_kernel<true><<<dim3(4, 4), 256, 0, stream>>>(hb0, h1_w, hb1, 2000, 1000, 500);
  bias_init_kernel<<<2, 256, 0, stream>>>(h2_b, hb2, 500);
  fc_splitk_kernel<true><<<dim3(2, 2), 256, 0, stream>>>(hb1, h2_w, hb2, 1000, 500, 500);
  final_fc_kernel<<<1, 512, 0, stream>>>(hb2, fc_w, fc_b, (float*)d_out);
}

// Round 8
// 1670.344 us; speedup vs baseline: 1.6560x; 1.3038x over previous
//
#include <hip/hip_runtime.h>
#include <hip/hip_fp16.h>
#include <cstddef>
#include <cstdint>

namespace {

typedef _Float16 h2_t __attribute__((ext_vector_type(2)));

constexpr int NPROT = 100000;
constexpr int EPROT = 1600000;
constexpr int NLIG  = 5000;
constexpr int ELIG  = 80000;

// ---------------- CSR construction ----------------

__global__ void hist_kernel(const int* __restrict__ dst, int* __restrict__ cnt, int e) {
  int i = blockIdx.x * 256 + threadIdx.x;
  if (i < e) atomicAdd(&cnt[dst[i]], 1);
}

// per-block (1024 elems) exclusive scan; also computes nrm = max(deg,1)^-0.5
__global__ void scan1_kernel(const int* __restrict__ cnt, int* __restrict__ rp,
                             int* __restrict__ bsum, float* __restrict__ nrm, int n) {
  __shared__ int wsum[4];
  int t = threadIdx.x;
  int base = blockIdx.x * 1024 + t * 4;
  int v0 = 0, v1 = 0, v2 = 0, v3 = 0;
  if (base + 3 < n) {
    int4 val = *(const int4*)(cnt + base);
    v0 = val.x; v1 = val.y; v2 = val.z; v3 = val.w;
  } else if (base < n) {
    v0 = cnt[base];
    if (base + 1 < n) v1 = cnt[base + 1];
    if (base + 2 < n) v2 = cnt[base + 2];
  }
  if (base < n)     nrm[base]     = 1.0f / sqrtf(fmaxf((float)v0, 1.0f));
  if (base + 1 < n) nrm[base + 1] = 1.0f / sqrtf(fmaxf((float)v1, 1.0f));
  if (base + 2 < n) nrm[base + 2] = 1.0f / sqrtf(fmaxf((float)v2, 1.0f));
  if (base + 3 < n) nrm[base + 3] = 1.0f / sqrtf(fmaxf((float)v3, 1.0f));
  int ts = v0 + v1 + v2 + v3;
  int lane = t & 63, wv = t >> 6;
  int incl = ts;
  #pragma unroll
  for (int off = 1; off < 64; off <<= 1) {
    int o = __shfl_up(incl, off, 64);
    if (lane >= off) incl += o;
  }
  if (lane == 63) wsum[wv] = incl;
  __syncthreads();
  int woff = 0;
  #pragma unroll
  for (int i = 0; i < 4; ++i) if (i < wv) woff += wsum[i];
  int excl = woff + incl - ts;
  int o0 = excl, o1 = o0 + v0, o2 = o1 + v1, o3 = o2 + v2;
  if (base + 3 < n) {
    *(int4*)(rp + base) = make_int4(o0, o1, o2, o3);
  } else if (base < n) {
    rp[base] = o0;
    if (base + 1 < n) rp[base + 1] = o1;
    if (base + 2 < n) rp[base + 2] = o2;
  }
  if (t == 255) bsum[blockIdx.x] = woff + incl;  // block total
}

// exclusive scan of <=256 block sums; writes grand total to rp[n]
__global__ void scan2_kernel(int* __restrict__ bsum, int nb, int* __restrict__ rp_end) {
  __shared__ int s[256];
  int t = threadIdx.x;
  int v = (t < nb) ? bsum[t] : 0;
  s[t] = v;
  __syncthreads();
  int val = v;
  for (int off = 1; off < 256; off <<= 1) {
    int add = (t >= off) ? s[t - off] : 0;
    __syncthreads();
    val += add;
    s[t] = val;
    __syncthreads();
  }
  if (t < nb) bsum[t] = val - v;  // exclusive
  if (t == 255) *rp_end = val;    // total
}

__global__ void scan3_kernel(int* __restrict__ rp, const int* __restrict__ bsum, int n) {
  int i = blockIdx.x * 256 + threadIdx.x;
  if (i < n) rp[i] += bsum[i >> 10];
}

__global__ void scatter_kernel(const int* __restrict__ src, const int* __restrict__ dst,
                               const int* __restrict__ rp, int* __restrict__ cur,
                               int* __restrict__ col, int e) {
  int i = blockIdx.x * 256 + threadIdx.x;
  if (i < e) {
    int d = dst[i];
    int p = rp[d] + atomicAdd(&cur[d], 1);
    col[p] = src[i];
  }
}

// ---------------- protein GNN ----------------
// g_k = nrm.*h_k stored fp16 in 16-feat chunks, padded width PD=ceil(DIN/16)*16
// (pads stay zero). Slab k (hop k) at gbase + k*slabh, slabh = n*80 halves.
// Chunk c, node v, slot s: addr = (c*n + v)*16 + s  (32B rows, L2-friendly).
// gathers: g_k = nrm^2 * sum_{src} g_{k-1}[src], one L2-resident chunk/pass.
// combine: y = b + (1/nrm) * sum_f g_cat[f] * W[f]  -> relu -> l2norm ->
//          next-layer g0 (in-place slab 0) or X (last layer).

// grid = NPASS*nbn (pass-major); 256 thr = 4 waves; wave = 4 nodes x 16 lanes
// (2 edge slots x 8 feat-pair lanes); 8 clamped branch-free loads in flight.
__global__ void gather_all_kernel(const __half* __restrict__ gin, const int* __restrict__ rp,
                                  const int* __restrict__ col, const float* __restrict__ nrm,
                                  __half* __restrict__ gout, int n, int nbn) {
  int pass = blockIdx.x / nbn;
  int bid = blockIdx.x - pass * nbn;
  int lane = threadIdx.x & 63, wv = threadIdx.x >> 6;
  int q = lane >> 4, r = lane & 15;
  int e_slot = r >> 3, f2 = r & 7;
  int v = bid * 16 + wv * 4 + q;
  bool vok = (v < n);
  int beg = 0, deg = 0;
  if (vok) { beg = rp[v]; deg = rp[v + 1] - beg; }
  const __half* gc = gin + (size_t)pass * n * 16;
  __half* go = gout + (size_t)pass * n * 16;
  float ax = 0.f, ay = 0.f;
  for (int base = 0; __any(base < deg); base += 16) {
    int ec = (base + r < deg) ? col[beg + base + r] : -1;
    #pragma unroll
    for (int js = 0; js < 16; js += 2) {
      int sl = (q << 4) + js + e_slot;
      int s0 = __shfl(ec, sl, 64);
      int idx = (s0 >= 0) ? s0 : 0;             // clamped: row 0 when invalid
      float m = (s0 >= 0) ? 1.f : 0.f;
      __half2 h2 = *(const __half2*)(gc + (size_t)idx * 16 + (f2 << 1));
      ax += m * __low2float(h2);
      ay += m * __high2float(h2);
    }
  }
  ax += __shfl_xor(ax, 8, 64);
  ay += __shfl_xor(ay, 8, 64);
  if (vok && e_slot == 0) {
    float nm = nrm[v];
    float nm2 = nm * nm;
    *(__half2*)(go + (size_t)v * 16 + (f2 << 1)) = __floats2half2_rn(ax * nm2, ay * nm2);
  }
}

// layer-1 only: g0 = x * nrm (chunked, pads zero)
template<int DIN>
__global__ void init_g0_kernel(const float* __restrict__ x, const float* __restrict__ nrm,
                               __half* __restrict__ g0, int n) {
  constexpr int PD = (DIN + 15) & ~15;
  int lane = threadIdx.x & 63;
  int v = blockIdx.x * 4 + (threadIdx.x >> 6);
  if (v >= n) return;
  float nm = nrm[v];
  for (int f = lane; f < PD; f += 64) {
    float val = (f < DIN) ? x[(size_t)v * DIN + f] * nm : 0.f;
    g0[(((size_t)(f >> 4) * n + v) << 4) + (f & 15)] = __float2half(val);
  }
}

// one pass per layer: reads g0..g4 slabs, W^T fp16 in LDS, fdot2 accumulate.
// Writes next-layer g0 in-place into slab 0 (safe: each node read-then-written
// by exactly one block), or X fp32 when LAST.
template<int DIN, int DOUT, bool LAST>
__global__ __launch_bounds__(256) void combine_kernel(
    const __half* __restrict__ gbase, const float* __restrict__ nrm,
    const float* __restrict__ W, const float* __restrict__ bias,
    __half* __restrict__ gnext, float* __restrict__ Xout,
    int n, int ngroups) {
  constexpr int PD  = (DIN + 15) & ~15;
  constexpr int KP2 = 5 * PD / 2;          // dwords per node h-row
  constexpr int STR = KP2 | 1;             // odd dword stride: conflict-free
  constexpr int PDN = (DOUT + 15) & ~15;
  __shared__ uint32_t WtU[DOUT * STR];
  __shared__ uint32_t hU[4 * STR];
  const size_t slabh = (size_t)n * 80;
  int tid = threadIdx.x;
  int lane = tid & 63, wv = tid >> 6;

  for (int i = tid; i < DOUT * STR; i += 256) WtU[i] = 0;
  __syncthreads();
  // stage W^T fp16: W row-major [5*DIN][DOUT] -> Wt[j][hop*PD + fl]
  for (int i = tid; i < 5 * DIN * DOUT; i += 256) {
    int f = i / DOUT, j = i - f * DOUT;
    int hop = f / DIN, fl = f - hop * DIN;
    int fp = hop * PD + fl;
    reinterpret_cast<__half*>(WtU)[(size_t)j * (2 * STR) + fp] = __float2half(W[i]);
  }
  __syncthreads();

  for (int grp = blockIdx.x; grp < ngroups; grp += (int)gridDim.x) {
    int v0 = grp * 4;
    for (int i = tid; i < 4 * KP2; i += 256) {
      int nl = i / KP2, w = i - nl * KP2;
      int v = v0 + nl;
      uint32_t val = 0;
      if (v < n) {
        int fg = w * 2;
        int hop = fg / PD, rem = fg - hop * PD;
        int chunk = rem >> 4, s = rem & 15;
        val = *reinterpret_cast<const uint32_t*>(
            gbase + (size_t)hop * slabh + (((size_t)chunk * n + v) << 4) + s);
      }
      hU[nl * STR + w] = val;
    }
    __syncthreads();
    int v = v0 + wv;
    if (v < n) {
      int cl = (lane < DOUT) ? lane : (DOUT - 1);
      const h2_t* wrow = reinterpret_cast<const h2_t*>(WtU + (size_t)cl * STR);
      const h2_t* hrow = reinterpret_cast<const h2_t*>(hU + (size_t)wv * STR);
      float a0 = 0.f, a1 = 0.f;
      #pragma unroll 8
      for (int w2 = 0; w2 < KP2; w2 += 2) {
        a0 = __builtin_amdgcn_fdot2(hrow[w2],     wrow[w2],     a0, false);
        a1 = __builtin_amdgcn_fdot2(hrow[w2 + 1], wrow[w2 + 1], a1, false);
      }
      float nm = nrm[v];
      float y = bias[cl] + (a0 + a1) * (1.f / nm);
      float val = (lane < DOUT) ? fmaxf(y, 0.f) : 0.f;
      float ss = val * val;
      #pragma unroll
      for (int off = 32; off > 0; off >>= 1) ss += __shfl_xor(ss, off, 64);
      float sc = 1.f / fmaxf(sqrtf(ss), 1e-12f);
      float xv = val * sc;
      if (LAST) {
        if (lane < DOUT) Xout[(size_t)v * DOUT + lane] = xv;
      } else {
        if (lane < PDN) {
          float gv = (lane < DOUT) ? xv * nm : 0.f;
          gnext[(((size_t)(lane >> 4) * n + v) << 4) + (lane & 15)] = __float2half(gv);
        }
      }
    }
    __syncthreads();
  }
}

// ---------------- ligand GNN: small-n fused hop (g is L2-resident) --------

template<int DIN, int GS, int DOUT>
__global__ void init_gemm_kernel(const float* __restrict__ x, const float* __restrict__ nrm,
                                 const float* __restrict__ W, const float* __restrict__ bias,
                                 __half* __restrict__ gout, float* __restrict__ y, int n) {
  int lane = threadIdx.x & 63;
  int v = blockIdx.x * 4 + (threadIdx.x >> 6);
  if (v >= n) return;
  float nm = nrm[v];
  const float* xr = x + (size_t)v * DIN;
  float hA = (lane < DIN) ? xr[lane] : 0.f;
  float hB = 0.f;
  if constexpr (DIN > 64) { if (lane + 64 < DIN) hB = xr[lane + 64]; }
  __half* go = gout + (size_t)v * GS;
  if (lane < DIN) go[lane] = __float2half(hA * nm);
  if constexpr (DIN > 64) { if (lane + 64 < DIN) go[lane + 64] = __float2half(hB * nm); }
  int cl = (lane < DOUT) ? lane : 0;
  float acc = bias[cl];
  const float* Wk = W + cl;
  #pragma unroll
  for (int f = 0; f < DIN; ++f) {
    float hf = (f < 64) ? __shfl(hA, f, 64) : __shfl(hB, f - 64, 64);
    acc += hf * Wk[(size_t)f * DOUT];
  }
  if (lane < DOUT) y[(size_t)v * DOUT + lane] = acc;
}

template<int DIN, int GS, int DOUT, bool WRITEG, bool FINAL>
__global__ void fused_hop_kernel(const __half* __restrict__ gin, const int* __restrict__ rp,
                                 const int* __restrict__ col, const float* __restrict__ nrm,
                                 const float* __restrict__ W, __half* __restrict__ gout,
                                 float* __restrict__ y, float* __restrict__ Xout,
                                 int k, int n) {
  int lane = threadIdx.x & 63;
  int v = blockIdx.x * 4 + (threadIdx.x >> 6);
  if (v >= n) return;
  int beg = rp[v], end = rp[v + 1];
  float a0 = 0.f, a1 = 0.f;
  for (int base = beg; base < end; base += 64) {
    int m = end - base; if (m > 64) m = 64;
    int myc = (lane < m) ? col[base + lane] : 0;
    int j = 0;
    for (; j + 8 <= m; j += 8) {
      int ss[8];
      float t0[8], t1[8];
      #pragma unroll
      for (int u = 0; u < 8; ++u) ss[u] = __shfl(myc, j + u, 64);
      #pragma unroll
      for (int u = 0; u < 8; ++u) {
        const __half* rr = gin + (size_t)ss[u] * GS;
        t0[u] = (lane < DIN) ? __half2float(rr[lane]) : 0.f;
        if constexpr (DIN > 64) t1[u] = (lane + 64 < DIN) ? __half2float(rr[lane + 64]) : 0.f;
      }
      #pragma unroll
      for (int u = 0; u < 8; ++u) {
        a0 += t0[u];
        if constexpr (DIN > 64) a1 += t1[u];
      }
    }
    for (; j < m; ++j) {
      int s = __shfl(myc, j, 64);
      const __half* rr = gin + (size_t)s * GS;
      if (lane < DIN) a0 += __half2float(rr[lane]);
      if constexpr (DIN > 64) { if (lane + 64 < DIN) a1 += __half2float(rr[lane + 64]); }
    }
  }
  float nm = nrm[v];
  float hA = a0 * nm, hB = a1 * nm;
  if (WRITEG) {
    __half* go = gout + (size_t)v * GS;
    if (lane < DIN) go[lane] = __float2half(hA * nm);
    if constexpr (DIN > 64) { if (lane + 64 < DIN) go[lane + 64] = __float2half(hB * nm); }
  }
  int cl = (lane < DOUT) ? lane : 0;
  float acc = 0.f;
  if (lane < DOUT) acc = y[(size_t)v * DOUT + lane];
  const float* Wk = W + (size_t)k * DIN * DOUT + cl;
  #pragma unroll
  for (int f = 0; f < DIN; ++f) {
    float hf = (f < 64) ? __shfl(hA, f, 64) : __shfl(hB, f - 64, 64);
    acc += hf * Wk[(size_t)f * DOUT];
  }
  if constexpr (FINAL) {
    float val = (lane < DOUT) ? fmaxf(acc, 0.f) : 0.f;
    float ss2 = val * val;
    #pragma unroll
    for (int off2 = 32; off2 > 0; off2 >>= 1) ss2 += __shfl_xor(ss2, off2, 64);
    float scale = 1.f / fmaxf(sqrtf(ss2), 1e-12f);
    if (lane < DOUT) Xout[(size_t)v * DOUT + lane] = val * scale;
  } else {
    if (lane < DOUT) y[(size_t)v * DOUT + lane] = acc;
  }
}

// hierarchical segment-max (values >= 0 post relu+l2norm; rep zeroed first)
__global__ void segmax_kernel(const float* __restrict__ X, const int* __restrict__ gid,
                              float* __restrict__ rep, int n, int row_off) {
  __shared__ float tab[4][45];
  __shared__ int gids[256];
  int t = threadIdx.x;
  for (int i = t; i < 4 * 45; i += 256) ((float*)tab)[i] = 0.f;
  int v0 = blockIdx.x * 256;
  int vend = v0 + 256; if (vend > n) vend = n;
  int nv = vend - v0;
  if (t < nv) gids[t] = gid[v0 + t];
  __syncthreads();
  int g0 = gids[0];
  int total = nv * 45;
  for (int i = t; i < total; i += 256) {
    int vl = i / 45, j = i - vl * 45;
    float val = X[(size_t)(v0 + vl) * 45 + j];
    int rel = gids[vl] - g0;
    if (rel >= 0 && rel < 4)
      atomicMax((unsigned int*)&tab[rel][j], __float_as_uint(val));
    else
      atomicMax((unsigned int*)&rep[(size_t)(row_off + gids[vl]) * 45 + j], __float_as_uint(val));
  }
  __syncthreads();
  for (int i = t; i < 4 * 45; i += 256) {
    float val = ((float*)tab)[i];
    if (val > 0.f) {
      int rel = i / 45, j = i - rel * 45;
      atomicMax((unsigned int*)&rep[(size_t)(row_off + g0 + rel) * 45 + j], __float_as_uint(val));
    }
  }
}

// ---------------- attention ----------------

__global__ void qkv_kernel(const float* __restrict__ rep, const float* __restrict__ w,
                           const float* __restrict__ b, float* __restrict__ qkv) {
  int i = blockIdx.x;      // 0..129
  int t = threadIdx.x;     // 256
  __shared__ float sr[45];
  if (t < 45) sr[t] = (i < 65) ? rep[(size_t)i * 45 + t] : 0.f;
  __syncthreads();
  if (t < 135) {
    float acc = b[t];
    #pragma unroll 5
    for (int d = 0; d < 45; ++d) acc += sr[d] * w[d * 135 + t];
    qkv[(size_t)i * 135 + t] = acc;
  }
}

__global__ void attn_kernel(const float* __restrict__ qkv, const float* __restrict__ proj_w,
                            const float* __restrict__ proj_b, float* __restrict__ ctx) {
  int i = blockIdx.x;     // query row
  int t = threadIdx.x;    // 256
  __shared__ float q[45];
  __shared__ float p[130];
  __shared__ float red[256];
  __shared__ float ao[45];
  if (t < 45) q[t] = qkv[(size_t)i * 135 + t];
  __syncthreads();
  float s = -1e30f;
  if (t < 130) {
    int j = t;
    float dot = 0.f;
    #pragma unroll 5
    for (int d = 0; d < 45; ++d) dot += q[d] * qkv[(size_t)j * 135 + 45 + d];
    dot *= 0.14907119849998599f;  // 45^-0.5
    bool mz;  // mask == 0 ?
    if (i == 64 && j == 64) mz = true;
    else if (i == 64 || j == 64) mz = false;
    else mz = !(i == j && i < 65);
    s = mz ? -1e9f : dot;
  }
  red[t] = s;
  __syncthreads();
  #pragma unroll
  for (int off = 128; off > 0; off >>= 1) {
    if (t < off) red[t] = fmaxf(red[t], red[t + off]);
    __syncthreads();
  }
  float mx = red[0];
  __syncthreads();
  float e = (t < 130) ? expf(s - mx) : 0.f;
  red[t] = e;
  __syncthreads();
  #pragma unroll
  for (int off = 128; off > 0; off >>= 1) {
    if (t < off) red[t] += red[t + off];
    __syncthreads();
  }
  float denom = red[0];
  __syncthreads();
  if (t < 130) p[t] = e / denom;
  __syncthreads();
  if (t < 45) {
    float acc = 0.f;
    for (int j = 0; j < 130; ++j) acc += p[j] * qkv[(size_t)j * 135 + 90 + t];
    ao[t] = acc;
  }
  __syncthreads();
  if (t < 45) {
    float pr = proj_b[t];
    #pragma unroll 5
    for (int e2 = 0; e2 < 45; ++e2) pr += ao[e2] * proj_w[e2 * 45 + t];
    ctx[(size_t)i * 45 + t] = pr;
  }
}

// ---------------- head MLP ----------------

__global__ void bias_init_kernel(const float* __restrict__ b, float* __restrict__ out, int n) {
  int i = blockIdx.x * 256 + threadIdx.x;
  if (i < n) out[i] = b[i];
}

template<bool RELU_IN>
__global__ void fc_splitk_kernel(const float* __restrict__ x, const float* __restrict__ W,
                                 float* __restrict__ out, int nin, int nout, int kchunk) {
  __shared__ float xs[1024];
  int k0 = blockIdx.y * kchunk;
  int k1 = k0 + kchunk; if (k1 > nin) k1 = nin;
  int len = k1 - k0;
  for (int i = threadIdx.x; i < len; i += blockDim.x) {
    float v = x[k0 + i];
    xs[i] = RELU_IN ? fmaxf(v, 0.f) : v;
  }
  __syncthreads();
  int j = blockIdx.x * blockDim.x + threadIdx.x;
  if (j < nout) {
    float acc = 0.f;
    const float* Wp = W + (size_t)k0 * nout + j;
    for (int i = 0; i < len; ++i) acc += xs[i] * Wp[(size_t)i * nout];
    atomicAdd(&out[j], acc);
  }
}

__global__ void final_fc_kernel(const float* __restrict__ x, const float* __restrict__ W,
                                const float* __restrict__ b, float* __restrict__ out) {
  __shared__ float red[512];
  int t = threadIdx.x;
  float acc = 0.f;
  if (t < 500) acc = fmaxf(x[t], 0.f) * W[t];
  red[t] = acc;
  __syncthreads();
  #pragma unroll
  for (int off = 256; off > 0; off >>= 1) {
    if (t < off) red[t] += red[t + off];
    __syncthreads();
  }
  if (t == 0) {
    float z = red[0] + b[0];
    out[0] = 1.f / (1.f + expf(-z));
  }
}

// ---------------- host-side orchestration ----------------

struct Bufs {
  __half* slabs;         // protein: 5 slabs of n*80 halves
  __half *ligA, *ligB;   // ligand ping/pong
  float *X, *Y, *nrm;
  int *cnt, *cur, *rp, *col, *bsum;
};

template<int DIN, int DOUT, bool LAST>
void run_layer_prot(const Bufs& g, const float* W, const float* b, int n, hipStream_t st) {
  constexpr int PD = (DIN + 15) & ~15;
  constexpr int NPASS = PD / 16;
  int nbn = (n + 15) / 16;
  size_t slabh = (size_t)n * 80;
  for (int k = 1; k <= 4; ++k)
    gather_all_kernel<<<NPASS * nbn, 256, 0, st>>>(g.slabs + (size_t)(k - 1) * slabh,
                                                   g.rp, g.col, g.nrm,
                                                   g.slabs + (size_t)k * slabh, n, nbn);
  int ngroups = (n + 3) / 4;
  combine_kernel<DIN, DOUT, LAST><<<768, 256, 0, st>>>(g.slabs, g.nrm, W, b,
                                                       g.slabs, g.X, n, ngroups);
}

template<int DIN, int GS, int DOUT>
void run_layer_lig(const float* xin, const Bufs& g, const float* W, const float* b,
                   int n, hipStream_t st) {
  int nb = (n + 3) / 4;
  init_gemm_kernel<DIN, GS, DOUT><<<nb, 256, 0, st>>>(xin, g.nrm, W, b, g.ligA, g.Y, n);
  const __half* gin = g.ligA;
  __half* gout = g.ligB;
  for (int k = 1; k <= 4; ++k) {
    if (k < 4)
      fused_hop_kernel<DIN, GS, DOUT, true, false><<<nb, 256, 0, st>>>(gin, g.rp, g.col, g.nrm, W, gout, g.Y, g.X, k, n);
    else
      fused_hop_kernel<DIN, GS, DOUT, false, true><<<nb, 256, 0, st>>>(gin, g.rp, g.col, g.nrm, W, gout, g.Y, g.X, 4, n);
    __half* t = (__half*)gin; gin = gout; gout = t;
  }
}

void build_csr(const int* src, const int* dst, const Bufs& g, int n, int e, hipStream_t st) {
  hipMemsetAsync(g.cnt, 0, (size_t)n * 4, st);
  hipMemsetAsync(g.cur, 0, (size_t)n * 4, st);
  hist_kernel<<<(e + 255) / 256, 256, 0, st>>>(dst, g.cnt, e);
  int nb1 = (n + 1023) / 1024;
  scan1_kernel<<<nb1, 256, 0, st>>>(g.cnt, g.rp, g.bsum, g.nrm, n);
  scan2_kernel<<<1, 256, 0, st>>>(g.bsum, nb1, g.rp + n);
  scan3_kernel<<<(n + 255) / 256, 256, 0, st>>>(g.rp, g.bsum, n);
  scatter_kernel<<<(e + 255) / 256, 256, 0, st>>>(src, dst, g.rp, g.cur, g.col, e);
}

} // namespace

extern "C" void kernel_launch(void* const* d_in, const int* in_sizes, int n_in,
                              void* d_out, int out_size, void* d_ws, size_t ws_size,
                              hipStream_t stream) {
  (void)in_sizes; (void)n_in; (void)out_size;

  const float* prot_x = (const float*)d_in[0];
  const float* lig_x  = (const float*)d_in[1];
  const float* pW[3] = {(const float*)d_in[2], (const float*)d_in[4], (const float*)d_in[6]};
  const float* pB[3] = {(const float*)d_in[3], (const float*)d_in[5], (const float*)d_in[7]};
  const float* lW[4] = {(const float*)d_in[8], (const float*)d_in[10], (const float*)d_in[12], (const float*)d_in[14]};
  const float* lB[4] = {(const float*)d_in[9], (const float*)d_in[11], (const float*)d_in[13], (const float*)d_in[15]};
  const float* qkv_w = (const float*)d_in[16];
  const float* qkv_b = (const float*)d_in[17];
  const float* proj_w = (const float*)d_in[18];
  const float* proj_b = (const float*)d_in[19];
  const float* h0_w = (const float*)d_in[20];
  const float* h0_b = (const float*)d_in[21];
  const float* h1_w = (const float*)d_in[22];
  const float* h1_b = (const float*)d_in[23];
  const float* h2_w = (const float*)d_in[24];
  const float* h2_b = (const float*)d_in[25];
  const float* fc_w = (const float*)d_in[26];
  const float* fc_b = (const float*)d_in[27];
  const int* prot_src = (const int*)d_in[28];
  const int* prot_dst = (const int*)d_in[29];
  const int* prot_gid = (const int*)d_in[30];
  const int* lig_src  = (const int*)d_in[31];
  const int* lig_dst  = (const int*)d_in[32];
  const int* lig_gid  = (const int*)d_in[33];

  // workspace carve-up
  char* w = (char*)d_ws;
  size_t off = 0;
  auto alloc = [&](size_t bytes) -> void* {
    void* p = w + off;
    off += (bytes + 255) & ~(size_t)255;
    return p;
  };
  __half* slabs = (__half*)alloc((size_t)5 * NPROT * 80 * 2);   // 80 MB: g0..g4
  __half* ligA  = (__half*)alloc((size_t)NLIG * 96 * 2);
  __half* ligB  = (__half*)alloc((size_t)NLIG * 96 * 2);
  float* X   = (float*)alloc((size_t)NPROT * 45 * 4);
  float* Y   = (float*)alloc((size_t)NLIG * 50 * 4);
  float* nrm = (float*)alloc((size_t)NPROT * 4);
  int* cnt   = (int*)alloc((size_t)NPROT * 4);
  int* cur   = (int*)alloc((size_t)NPROT * 4);
  int* rp    = (int*)alloc(((size_t)NPROT + 1) * 4);
  int* colb  = (int*)alloc((size_t)EPROT * 4);
  int* bsum  = (int*)alloc((size_t)256 * 4);
  float* rep = (float*)alloc((size_t)65 * 45 * 4);
  float* qkvb = (float*)alloc((size_t)130 * 135 * 4);
  float* ctx  = (float*)alloc((size_t)5850 * 4);
  float* hb0  = (float*)alloc((size_t)2000 * 4);
  float* hb1  = (float*)alloc((size_t)1000 * 4);
  float* hb2  = (float*)alloc((size_t)500 * 4);
  if (off > ws_size) return;  // workspace too small: fail loudly via validation

  hipMemsetAsync(rep, 0, (size_t)65 * 45 * 4, stream);

  Bufs g{slabs, ligA, ligB, X, Y, nrm, cnt, cur, rp, colb, bsum};

  // ---- protein GNN (chunked L2-resident gathers + one combine per layer) ----
  build_csr(prot_src, prot_dst, g, NPROT, EPROT, stream);
  init_g0_kernel<74><<<(NPROT + 3) / 4, 256, 0, stream>>>(prot_x, g.nrm, g.slabs, NPROT);
  run_layer_prot<74, 50, false>(g, pW[0], pB[0], NPROT, stream);
  run_layer_prot<50, 45, false>(g, pW[1], pB[1], NPROT, stream);
  run_layer_prot<45, 45, true >(g, pW[2], pB[2], NPROT, stream);
  segmax_kernel<<<(NPROT + 255) / 256, 256, 0, stream>>>(g.X, prot_gid, rep, NPROT, 1);

  // ---- ligand GNN (small; fused path) ----
  build_csr(lig_src, lig_dst, g, NLIG, ELIG, stream);
  run_layer_lig<74, 96, 50>(lig_x, g, lW[0], lB[0], NLIG, stream);
  run_layer_lig<50, 64, 45>(g.X, g, lW[1], lB[1], NLIG, stream);
  run_layer_lig<45, 64, 45>(g.X, g, lW[2], lB[2], NLIG, stream);
  run_layer_lig<45, 64, 45>(g.X, g, lW[3], lB[3], NLIG, stream);
  segmax_kernel<<<(NLIG + 255) / 256, 256, 0, stream>>>(g.X, lig_gid, rep, NLIG, 0);

  // ---- attention ----
  qkv_kernel<<<130, 256, 0, stream>>>(rep, qkv_w, qkv_b, qkvb);
  attn_kernel<<<130, 256, 0, stream>>>(qkvb, proj_w, proj_b, ctx);

  // ---- head MLP ----
  bias_init_kernel<<<8, 256, 0, stream>>>(h0_b, hb0, 2000);
  fc_splitk_kernel<false><<<dim3(8, 8), 256, 0, stream>>>(ctx, h0_w, hb0, 5850, 2000, 732);
  bias_init_kernel<<<4, 256, 0, stream>>>(h1_b, hb1, 1000);
  fc_splitk_kernel<true><<<dim3(4, 4), 256, 0, stream>>>(hb0, h1_w, hb1, 2000, 1000, 500);
  bias_init_kernel<<<2, 256, 0, stream>>>(h2_b, hb2, 500);
  fc_splitk_kernel<true><<<dim3(2, 2), 256, 0, stream>>>(hb1, h2_w, hb2, 1000, 500, 500);
  final_fc_kernel<<<1, 512, 0, stream>>>(hb2, fc_w, fc_b, (float*)d_out);
}

// Round 9
// 1541.507 us; speedup vs baseline: 1.7944x; 1.0836x over previous
//
#include <hip/hip_runtime.h>
#include <hip/hip_fp16.h>
#include <cstddef>
#include <cstdint>

namespace {

constexpr int NPROT = 100000;
constexpr int EPROT = 1600000;
constexpr int NLIG  = 5000;
constexpr int ELIG  = 80000;

// ---------------- CSR construction ----------------

__global__ void hist_kernel(const int* __restrict__ dst, int* __restrict__ cnt, int e) {
  int i = blockIdx.x * 256 + threadIdx.x;
  if (i < e) atomicAdd(&cnt[dst[i]], 1);
}

// per-block (1024 elems) exclusive scan; also computes nrm = max(deg,1)^-0.5
__global__ void scan1_kernel(const int* __restrict__ cnt, int* __restrict__ rp,
                             int* __restrict__ bsum, float* __restrict__ nrm, int n) {
  __shared__ int wsum[4];
  int t = threadIdx.x;
  int base = blockIdx.x * 1024 + t * 4;
  int v0 = 0, v1 = 0, v2 = 0, v3 = 0;
  if (base + 3 < n) {
    int4 val = *(const int4*)(cnt + base);
    v0 = val.x; v1 = val.y; v2 = val.z; v3 = val.w;
  } else if (base < n) {
    v0 = cnt[base];
    if (base + 1 < n) v1 = cnt[base + 1];
    if (base + 2 < n) v2 = cnt[base + 2];
  }
  if (base < n)     nrm[base]     = 1.0f / sqrtf(fmaxf((float)v0, 1.0f));
  if (base + 1 < n) nrm[base + 1] = 1.0f / sqrtf(fmaxf((float)v1, 1.0f));
  if (base + 2 < n) nrm[base + 2] = 1.0f / sqrtf(fmaxf((float)v2, 1.0f));
  if (base + 3 < n) nrm[base + 3] = 1.0f / sqrtf(fmaxf((float)v3, 1.0f));
  int ts = v0 + v1 + v2 + v3;
  int lane = t & 63, wv = t >> 6;
  int incl = ts;
  #pragma unroll
  for (int off = 1; off < 64; off <<= 1) {
    int o = __shfl_up(incl, off, 64);
    if (lane >= off) incl += o;
  }
  if (lane == 63) wsum[wv] = incl;
  __syncthreads();
  int woff = 0;
  #pragma unroll
  for (int i = 0; i < 4; ++i) if (i < wv) woff += wsum[i];
  int excl = woff + incl - ts;
  int o0 = excl, o1 = o0 + v0, o2 = o1 + v1, o3 = o2 + v2;
  if (base + 3 < n) {
    *(int4*)(rp + base) = make_int4(o0, o1, o2, o3);
  } else if (base < n) {
    rp[base] = o0;
    if (base + 1 < n) rp[base + 1] = o1;
    if (base + 2 < n) rp[base + 2] = o2;
  }
  if (t == 255) bsum[blockIdx.x] = woff + incl;  // block total
}

// exclusive scan of <=256 block sums; writes grand total to rp[n]
__global__ void scan2_kernel(int* __restrict__ bsum, int nb, int* __restrict__ rp_end) {
  __shared__ int s[256];
  int t = threadIdx.x;
  int v = (t < nb) ? bsum[t] : 0;
  s[t] = v;
  __syncthreads();
  int val = v;
  for (int off = 1; off < 256; off <<= 1) {
    int add = (t >= off) ? s[t - off] : 0;
    __syncthreads();
    val += add;
    s[t] = val;
    __syncthreads();
  }
  if (t < nb) bsum[t] = val - v;  // exclusive
  if (t == 255) *rp_end = val;    // total
}

__global__ void scan3_kernel(int* __restrict__ rp, const int* __restrict__ bsum, int n) {
  int i = blockIdx.x * 256 + threadIdx.x;
  if (i < n) rp[i] += bsum[i >> 10];
}

__global__ void scatter_kernel(const int* __restrict__ src, const int* __restrict__ dst,
                               const int* __restrict__ rp, int* __restrict__ cur,
                               int* __restrict__ col, int e) {
  int i = blockIdx.x * 256 + threadIdx.x;
  if (i < e) {
    int d = dst[i];
    int p = rp[d] + atomicAdd(&cur[d], 1);
    col[p] = src[i];
  }
}

// ---------------- protein GNN ----------------
// g_k = nrm.*h_k stored fp16 in 16-feat chunks, padded width PD=ceil(DIN/16)*16
// (pads stay zero). Slab k (hop k) at gbase + k*slabh, slabh = n*80 halves.
// Chunk c, node v, slot s: addr = (c*n + v)*16 + s  (32B rows, L2-friendly).
// gathers: g_k = nrm^2 * sum_{src} g_{k-1}[src], one L2-resident chunk/pass.
// combine: thread-per-node; y = b + (1/nrm)*sum_f g_cat[f]*Wp[f]; weights read
// at wave-uniform indices (scalar loads); relu+l2norm fused; writes next g0
// in-place into slab 0 (each thread touches only its own node's rows).

// grid = NPASS*nbn (pass-major); 256 thr = 4 waves; wave = 4 nodes x 16 lanes
// (2 edge slots x 8 feat-pair lanes); 8 clamped branch-free loads in flight.
__global__ void gather_all_kernel(const __half* __restrict__ gin, const int* __restrict__ rp,
                                  const int* __restrict__ col, const float* __restrict__ nrm,
                                  __half* __restrict__ gout, int n, int nbn) {
  int pass = blockIdx.x / nbn;
  int bid = blockIdx.x - pass * nbn;
  int lane = threadIdx.x & 63, wv = threadIdx.x >> 6;
  int q = lane >> 4, r = lane & 15;
  int e_slot = r >> 3, f2 = r & 7;
  int v = bid * 16 + wv * 4 + q;
  bool vok = (v < n);
  int beg = 0, deg = 0;
  if (vok) { beg = rp[v]; deg = rp[v + 1] - beg; }
  const __half* gc = gin + (size_t)pass * n * 16;
  __half* go = gout + (size_t)pass * n * 16;
  float ax = 0.f, ay = 0.f;
  for (int base = 0; __any(base < deg); base += 16) {
    int ec = (base + r < deg) ? col[beg + base + r] : -1;
    #pragma unroll
    for (int js = 0; js < 16; js += 2) {
      int sl = (q << 4) + js + e_slot;
      int s0 = __shfl(ec, sl, 64);
      int idx = (s0 >= 0) ? s0 : 0;             // clamped: row 0 when invalid
      float m = (s0 >= 0) ? 1.f : 0.f;
      __half2 h2 = *(const __half2*)(gc + (size_t)idx * 16 + (f2 << 1));
      ax += m * __low2float(h2);
      ay += m * __high2float(h2);
    }
  }
  ax += __shfl_xor(ax, 8, 64);
  ay += __shfl_xor(ay, 8, 64);
  if (vok && e_slot == 0) {
    float nm = nrm[v];
    float nm2 = nm * nm;
    *(__half2*)(go + (size_t)v * 16 + (f2 << 1)) = __floats2half2_rn(ax * nm2, ay * nm2);
  }
}

// layer-1 only: g0 = x * nrm (chunked, pads zero)
template<int DIN>
__global__ void init_g0_kernel(const float* __restrict__ x, const float* __restrict__ nrm,
                               __half* __restrict__ g0, int n) {
  constexpr int PD = (DIN + 15) & ~15;
  int lane = threadIdx.x & 63;
  int v = blockIdx.x * 4 + (threadIdx.x >> 6);
  if (v >= n) return;
  float nm = nrm[v];
  for (int f = lane; f < PD; f += 64) {
    float val = (f < DIN) ? x[(size_t)v * DIN + f] * nm : 0.f;
    g0[(((size_t)(f >> 4) * n + v) << 4) + (f & 15)] = __float2half(val);
  }
}

// pad W [5*DIN][DOUT] -> Wp [5*PD][DOUT] (pad rows zero)
__global__ void padw_kernel(const float* __restrict__ W, float* __restrict__ Wp,
                            int din, int dout, int pd) {
  int i = blockIdx.x * 256 + threadIdx.x;
  int total = 5 * pd * dout;
  if (i >= total) return;
  int f = i / dout, j = i - f * dout;
  int hop = f / pd, rem = f - hop * pd;
  Wp[i] = (rem < din) ? W[(size_t)(hop * din + rem) * dout + j] : 0.f;
}

// thread-per-node combine: acc[DOUT] in VGPRs, W via wave-uniform scalar loads
template<int DIN, int DOUT, bool LAST>
__global__ __launch_bounds__(256) void combine_kernel(
    const __half* __restrict__ gbase, const float* __restrict__ nrm,
    const float* __restrict__ Wp, const float* __restrict__ bias,
    __half* __restrict__ gnext, float* __restrict__ Xout, int n) {
  constexpr int PD = (DIN + 15) & ~15;
  constexpr int NCH = PD / 16;
  constexpr int PDN = (DOUT + 15) & ~15;
  int v = blockIdx.x * 256 + threadIdx.x;
  if (v >= n) return;
  const size_t slabh = (size_t)n * 80;
  float acc[DOUT];
  #pragma unroll
  for (int j = 0; j < DOUT; ++j) acc[j] = 0.f;
  const float* wr = Wp;
  for (int hop = 0; hop < 5; ++hop) {
    const __half* hrow = gbase + (size_t)hop * slabh + ((size_t)v << 4);
    for (int ch = 0; ch < NCH; ++ch) {
      float h[16];
      #pragma unroll
      for (int s2 = 0; s2 < 8; ++s2) {
        __half2 hh = *(const __half2*)(hrow + s2 * 2);
        h[2 * s2]     = __low2float(hh);
        h[2 * s2 + 1] = __high2float(hh);
      }
      #pragma unroll
      for (int s = 0; s < 16; ++s) {
        #pragma unroll
        for (int j = 0; j < DOUT; ++j) acc[j] += h[s] * wr[s * DOUT + j];
      }
      wr += 16 * DOUT;
      hrow += ((size_t)n << 4);
    }
  }
  float rn = 1.f / nrm[v];
  float ss = 0.f;
  #pragma unroll
  for (int j = 0; j < DOUT; ++j) {
    float y = bias[j] + acc[j] * rn;
    y = fmaxf(y, 0.f);
    acc[j] = y;
    ss += y * y;
  }
  float sc = 1.f / fmaxf(sqrtf(ss), 1e-12f);
  if (LAST) {
    #pragma unroll
    for (int j = 0; j < DOUT; ++j) Xout[(size_t)v * DOUT + j] = acc[j] * sc;
  } else {
    float nm = nrm[v];
    #pragma unroll
    for (int ch = 0; ch < PDN / 16; ++ch) {
      __half* go = gnext + (((size_t)ch * n + v) << 4);
      #pragma unroll
      for (int s2 = 0; s2 < 8; ++s2) {
        int j0 = ch * 16 + s2 * 2, j1 = j0 + 1;
        float a = (j0 < DOUT) ? acc[j0] * sc * nm : 0.f;
        float b = (j1 < DOUT) ? acc[j1] * sc * nm : 0.f;
        *(__half2*)(go + s2 * 2) = __floats2half2_rn(a, b);
      }
    }
  }
}

// ---------------- ligand GNN: small-n fused hop (g is L2-resident) --------

template<int DIN, int GS, int DOUT>
__global__ void init_gemm_kernel(const float* __restrict__ x, const float* __restrict__ nrm,
                                 const float* __restrict__ W, const float* __restrict__ bias,
                                 __half* __restrict__ gout, float* __restrict__ y, int n) {
  int lane = threadIdx.x & 63;
  int v = blockIdx.x * 4 + (threadIdx.x >> 6);
  if (v >= n) return;
  float nm = nrm[v];
  const float* xr = x + (size_t)v * DIN;
  float hA = (lane < DIN) ? xr[lane] : 0.f;
  float hB = 0.f;
  if constexpr (DIN > 64) { if (lane + 64 < DIN) hB = xr[lane + 64]; }
  __half* go = gout + (size_t)v * GS;
  if (lane < DIN) go[lane] = __float2half(hA * nm);
  if constexpr (DIN > 64) { if (lane + 64 < DIN) go[lane + 64] = __float2half(hB * nm); }
  int cl = (lane < DOUT) ? lane : 0;
  float acc = bias[cl];
  const float* Wk = W + cl;
  #pragma unroll
  for (int f = 0; f < DIN; ++f) {
    float hf = (f < 64) ? __shfl(hA, f, 64) : __shfl(hB, f - 64, 64);
    acc += hf * Wk[(size_t)f * DOUT];
  }
  if (lane < DOUT) y[(size_t)v * DOUT + lane] = acc;
}

template<int DIN, int GS, int DOUT, bool WRITEG, bool FINAL>
__global__ void fused_hop_kernel(const __half* __restrict__ gin, const int* __restrict__ rp,
                                 const int* __restrict__ col, const float* __restrict__ nrm,
                                 const float* __restrict__ W, __half* __restrict__ gout,
                                 float* __restrict__ y, float* __restrict__ Xout,
                                 int k, int n) {
  int lane = threadIdx.x & 63;
  int v = blockIdx.x * 4 + (threadIdx.x >> 6);
  if (v >= n) return;
  int beg = rp[v], end = rp[v + 1];
  float a0 = 0.f, a1 = 0.f;
  for (int base = beg; base < end; base += 64) {
    int m = end - base; if (m > 64) m = 64;
    int myc = (lane < m) ? col[base + lane] : 0;
    int j = 0;
    for (; j + 8 <= m; j += 8) {
      int ss[8];
      float t0[8], t1[8];
      #pragma unroll
      for (int u = 0; u < 8; ++u) ss[u] = __shfl(myc, j + u, 64);
      #pragma unroll
      for (int u = 0; u < 8; ++u) {
        const __half* rr = gin + (size_t)ss[u] * GS;
        t0[u] = (lane < DIN) ? __half2float(rr[lane]) : 0.f;
        if constexpr (DIN > 64) t1[u] = (lane + 64 < DIN) ? __half2float(rr[lane + 64]) : 0.f;
      }
      #pragma unroll
      for (int u = 0; u < 8; ++u) {
        a0 += t0[u];
        if constexpr (DIN > 64) a1 += t1[u];
      }
    }
    for (; j < m; ++j) {
      int s = __shfl(myc, j, 64);
      const __half* rr = gin + (size_t)s * GS;
      if (lane < DIN) a0 += __half2float(rr[lane]);
      if constexpr (DIN > 64) { if (lane + 64 < DIN) a1 += __half2float(rr[lane + 64]); }
    }
  }
  float nm = nrm[v];
  float hA = a0 * nm, hB = a1 * nm;
  if (WRITEG) {
    __half* go = gout + (size_t)v * GS;
    if (lane < DIN) go[lane] = __float2half(hA * nm);
    if constexpr (DIN > 64) { if (lane + 64 < DIN) go[lane + 64] = __float2half(hB * nm); }
  }
  int cl = (lane < DOUT) ? lane : 0;
  float acc = 0.f;
  if (lane < DOUT) acc = y[(size_t)v * DOUT + lane];
  const float* Wk = W + (size_t)k * DIN * DOUT + cl;
  #pragma unroll
  for (int f = 0; f < DIN; ++f) {
    float hf = (f < 64) ? __shfl(hA, f, 64) : __shfl(hB, f - 64, 64);
    acc += hf * Wk[(size_t)f * DOUT];
  }
  if constexpr (FINAL) {
    float val = (lane < DOUT) ? fmaxf(acc, 0.f) : 0.f;
    float ss2 = val * val;
    #pragma unroll
    for (int off2 = 32; off2 > 0; off2 >>= 1) ss2 += __shfl_xor(ss2, off2, 64);
    float scale = 1.f / fmaxf(sqrtf(ss2), 1e-12f);
    if (lane < DOUT) Xout[(size_t)v * DOUT + lane] = val * scale;
  } else {
    if (lane < DOUT) y[(size_t)v * DOUT + lane] = acc;
  }
}

// hierarchical segment-max (values >= 0 post relu+l2norm; rep zeroed first)
__global__ void segmax_kernel(const float* __restrict__ X, const int* __restrict__ gid,
                              float* __restrict__ rep, int n, int row_off) {
  __shared__ float tab[4][45];
  __shared__ int gids[256];
  int t = threadIdx.x;
  for (int i = t; i < 4 * 45; i += 256) ((float*)tab)[i] = 0.f;
  int v0 = blockIdx.x * 256;
  int vend = v0 + 256; if (vend > n) vend = n;
  int nv = vend - v0;
  if (t < nv) gids[t] = gid[v0 + t];
  __syncthreads();
  int g0 = gids[0];
  int total = nv * 45;
  for (int i = t; i < total; i += 256) {
    int vl = i / 45, j = i - vl * 45;
    float val = X[(size_t)(v0 + vl) * 45 + j];
    int rel = gids[vl] - g0;
    if (rel >= 0 && rel < 4)
      atomicMax((unsigned int*)&tab[rel][j], __float_as_uint(val));
    else
      atomicMax((unsigned int*)&rep[(size_t)(row_off + gids[vl]) * 45 + j], __float_as_uint(val));
  }
  __syncthreads();
  for (int i = t; i < 4 * 45; i += 256) {
    float val = ((float*)tab)[i];
    if (val > 0.f) {
      int rel = i / 45, j = i - rel * 45;
      atomicMax((unsigned int*)&rep[(size_t)(row_off + g0 + rel) * 45 + j], __float_as_uint(val));
    }
  }
}

// ---------------- attention ----------------

__global__ void qkv_kernel(const float* __restrict__ rep, const float* __restrict__ w,
                           const float* __restrict__ b, float* __restrict__ qkv) {
  int i = blockIdx.x;      // 0..129
  int t = threadIdx.x;     // 256
  __shared__ float sr[45];
  if (t < 45) sr[t] = (i < 65) ? rep[(size_t)i * 45 + t] : 0.f;
  __syncthreads();
  if (t < 135) {
    float acc = b[t];
    #pragma unroll 5
    for (int d = 0; d < 45; ++d) acc += sr[d] * w[d * 135 + t];
    qkv[(size_t)i * 135 + t] = acc;
  }
}

__global__ void attn_kernel(const float* __restrict__ qkv, const float* __restrict__ proj_w,
                            const float* __restrict__ proj_b, float* __restrict__ ctx) {
  int i = blockIdx.x;     // query row
  int t = threadIdx.x;    // 256
  __shared__ float q[45];
  __shared__ float p[130];
  __shared__ float red[256];
  __shared__ float ao[45];
  if (t < 45) q[t] = qkv[(size_t)i * 135 + t];
  __syncthreads();
  float s = -1e30f;
  if (t < 130) {
    int j = t;
    float dot = 0.f;
    #pragma unroll 5
    for (int d = 0; d < 45; ++d) dot += q[d] * qkv[(size_t)j * 135 + 45 + d];
    dot *= 0.14907119849998599f;  // 45^-0.5
    bool mz;  // mask == 0 ?
    if (i == 64 && j == 64) mz = true;
    else if (i == 64 || j == 64) mz = false;
    else mz = !(i == j && i < 65);
    s = mz ? -1e9f : dot;
  }
  red[t] = s;
  __syncthreads();
  #pragma unroll
  for (int off = 128; off > 0; off >>= 1) {
    if (t < off) red[t] = fmaxf(red[t], red[t + off]);
    __syncthreads();
  }
  float mx = red[0];
  __syncthreads();
  float e = (t < 130) ? expf(s - mx) : 0.f;
  red[t] = e;
  __syncthreads();
  #pragma unroll
  for (int off = 128; off > 0; off >>= 1) {
    if (t < off) red[t] += red[t + off];
    __syncthreads();
  }
  float denom = red[0];
  __syncthreads();
  if (t < 130) p[t] = e / denom;
  __syncthreads();
  if (t < 45) {
    float acc = 0.f;
    for (int j = 0; j < 130; ++j) acc += p[j] * qkv[(size_t)j * 135 + 90 + t];
    ao[t] = acc;
  }
  __syncthreads();
  if (t < 45) {
    float pr = proj_b[t];
    #pragma unroll 5
    for (int e2 = 0; e2 < 45; ++e2) pr += ao[e2] * proj_w[e2 * 45 + t];
    ctx[(size_t)i * 45 + t] = pr;
  }
}

// ---------------- head MLP ----------------

__global__ void bias_init_kernel(const float* __restrict__ b, float* __restrict__ out, int n) {
  int i = blockIdx.x * 256 + threadIdx.x;
  if (i < n) out[i] = b[i];
}

template<bool RELU_IN>
__global__ void fc_splitk_kernel(const float* __restrict__ x, const float* __restrict__ W,
                                 float* __restrict__ out, int nin, int nout, int kchunk) {
  __shared__ float xs[1024];
  int k0 = blockIdx.y * kchunk;
  int k1 = k0 + kchunk; if (k1 > nin) k1 = nin;
  int len = k1 - k0;
  for (int i = threadIdx.x; i < len; i += blockDim.x) {
    float v = x[k0 + i];
    xs[i] = RELU_IN ? fmaxf(v, 0.f) : v;
  }
  __syncthreads();
  int j = blockIdx.x * blockDim.x + threadIdx.x;
  if (j < nout) {
    float acc = 0.f;
    const float* Wp = W + (size_t)k0 * nout + j;
    for (int i = 0; i < len; ++i) acc += xs[i] * Wp[(size_t)i * nout];
    atomicAdd(&out[j], acc);
  }
}

__global__ void final_fc_kernel(const float* __restrict__ x, const float* __restrict__ W,
                                const float* __restrict__ b, float* __restrict__ out) {
  __shared__ float red[512];
  int t = threadIdx.x;
  float acc = 0.f;
  if (t < 500) acc = fmaxf(x[t], 0.f) * W[t];
  red[t] = acc;
  __syncthreads();
  #pragma unroll
  for (int off = 256; off > 0; off >>= 1) {
    if (t < off) red[t] += red[t + off];
    __syncthreads();
  }
  if (t == 0) {
    float z = red[0] + b[0];
    out[0] = 1.f / (1.f + expf(-z));
  }
}

// ---------------- host-side orchestration ----------------

struct Bufs {
  __half* slabs;         // protein: 5 slabs of n*80 halves
  __half *ligA, *ligB;   // ligand ping/pong
  float *X, *Y, *nrm, *Wp;
  int *cnt, *cur, *rp, *col, *bsum;
};

template<int DIN, int DOUT, bool LAST>
void run_layer_prot(const Bufs& g, const float* W, const float* b, int n, hipStream_t st) {
  constexpr int PD = (DIN + 15) & ~15;
  constexpr int NPASS = PD / 16;
  int nbn = (n + 15) / 16;
  size_t slabh = (size_t)n * 80;
  for (int k = 1; k <= 4; ++k)
    gather_all_kernel<<<NPASS * nbn, 256, 0, st>>>(g.slabs + (size_t)(k - 1) * slabh,
                                                   g.rp, g.col, g.nrm,
                                                   g.slabs + (size_t)k * slabh, n, nbn);
  int wtotal = 5 * PD * DOUT;
  padw_kernel<<<(wtotal + 255) / 256, 256, 0, st>>>(W, g.Wp, DIN, DOUT, PD);
  combine_kernel<DIN, DOUT, LAST><<<(n + 255) / 256, 256, 0, st>>>(
      g.slabs, g.nrm, g.Wp, b, g.slabs, g.X, n);
}

template<int DIN, int GS, int DOUT>
void run_layer_lig(const float* xin, const Bufs& g, const float* W, const float* b,
                   int n, hipStream_t st) {
  int nb = (n + 3) / 4;
  init_gemm_kernel<DIN, GS, DOUT><<<nb, 256, 0, st>>>(xin, g.nrm, W, b, g.ligA, g.Y, n);
  const __half* gin = g.ligA;
  __half* gout = g.ligB;
  for (int k = 1; k <= 4; ++k) {
    if (k < 4)
      fused_hop_kernel<DIN, GS, DOUT, true, false><<<nb, 256, 0, st>>>(gin, g.rp, g.col, g.nrm, W, gout, g.Y, g.X, k, n);
    else
      fused_hop_kernel<DIN, GS, DOUT, false, true><<<nb, 256, 0, st>>>(gin, g.rp, g.col, g.nrm, W, gout, g.Y, g.X, 4, n);
    __half* t = (__half*)gin; gin = gout; gout = t;
  }
}

void build_csr(const int* src, const int* dst, const Bufs& g, int n, int e, hipStream_t st) {
  hipMemsetAsync(g.cnt, 0, (size_t)n * 4, st);
  hipMemsetAsync(g.cur, 0, (size_t)n * 4, st);
  hist_kernel<<<(e + 255) / 256, 256, 0, st>>>(dst, g.cnt, e);
  int nb1 = (n + 1023) / 1024;
  scan1_kernel<<<nb1, 256, 0, st>>>(g.cnt, g.rp, g.bsum, g.nrm, n);
  scan2_kernel<<<1, 256, 0, st>>>(g.bsum, nb1, g.rp + n);
  scan3_kernel<<<(n + 255) / 256, 256, 0, st>>>(g.rp, g.bsum, n);
  scatter_kernel<<<(e + 255) / 256, 256, 0, st>>>(src, dst, g.rp, g.cur, g.col, e);
}

} // namespace

extern "C" void kernel_launch(void* const* d_in, const int* in_sizes, int n_in,
                              void* d_out, int out_size, void* d_ws, size_t ws_size,
                              hipStream_t stream) {
  (void)in_sizes; (void)n_in; (void)out_size;

  const float* prot_x = (const float*)d_in[0];
  const float* lig_x  = (const float*)d_in[1];
  const float* pW[3] = {(const float*)d_in[2], (const float*)d_in[4], (const float*)d_in[6]};
  const float* pB[3] = {(const float*)d_in[3], (const float*)d_in[5], (const float*)d_in[7]};
  const float* lW[4] = {(const float*)d_in[8], (const float*)d_in[10], (const float*)d_in[12], (const float*)d_in[14]};
  const float* lB[4] = {(const float*)d_in[9], (const float*)d_in[11], (const float*)d_in[13], (const float*)d_in[15]};
  const float* qkv_w = (const float*)d_in[16];
  const float* qkv_b = (const float*)d_in[17];
  const float* proj_w = (const float*)d_in[18];
  const float* proj_b = (const float*)d_in[19];
  const float* h0_w = (const float*)d_in[20];
  const float* h0_b = (const float*)d_in[21];
  const float* h1_w = (const float*)d_in[22];
  const float* h1_b = (const float*)d_in[23];
  const float* h2_w = (const float*)d_in[24];
  const float* h2_b = (const float*)d_in[25];
  const float* fc_w = (const float*)d_in[26];
  const float* fc_b = (const float*)d_in[27];
  const int* prot_src = (const int*)d_in[28];
  const int* prot_dst = (const int*)d_in[29];
  const int* prot_gid = (const int*)d_in[30];
  const int* lig_src  = (const int*)d_in[31];
  const int* lig_dst  = (const int*)d_in[32];
  const int* lig_gid  = (const int*)d_in[33];

  // workspace carve-up
  char* w = (char*)d_ws;
  size_t off = 0;
  auto alloc = [&](size_t bytes) -> void* {
    void* p = w + off;
    off += (bytes + 255) & ~(size_t)255;
    return p;
  };
  __half* slabs = (__half*)alloc((size_t)5 * NPROT * 80 * 2);   // 80 MB: g0..g4
  __half* ligA  = (__half*)alloc((size_t)NLIG * 96 * 2);
  __half* ligB  = (__half*)alloc((size_t)NLIG * 96 * 2);
  float* X   = (float*)alloc((size_t)NPROT * 45 * 4);
  float* Y   = (float*)alloc((size_t)NLIG * 50 * 4);
  float* nrm = (float*)alloc((size_t)NPROT * 4);
  float* Wp  = (float*)alloc((size_t)5 * 80 * 50 * 4);
  int* cnt   = (int*)alloc((size_t)NPROT * 4);
  int* cur   = (int*)alloc((size_t)NPROT * 4);
  int* rp    = (int*)alloc(((size_t)NPROT + 1) * 4);
  int* colb  = (int*)alloc((size_t)EPROT * 4);
  int* bsum  = (int*)alloc((size_t)256 * 4);
  float* rep = (float*)alloc((size_t)65 * 45 * 4);
  float* qkvb = (float*)alloc((size_t)130 * 135 * 4);
  float* ctx  = (float*)alloc((size_t)5850 * 4);
  float* hb0  = (float*)alloc((size_t)2000 * 4);
  float* hb1  = (float*)alloc((size_t)1000 * 4);
  float* hb2  = (float*)alloc((size_t)500 * 4);
  if (off > ws_size) return;  // workspace too small: fail loudly via validation

  hipMemsetAsync(rep, 0, (size_t)65 * 45 * 4, stream);

  Bufs g{slabs, ligA, ligB, X, Y, nrm, Wp, cnt, cur, rp, colb, bsum};

  // ---- protein GNN (chunked L2-resident gathers + thread-per-node combine) --
  build_csr(prot_src, prot_dst, g, NPROT, EPROT, stream);
  init_g0_kernel<74><<<(NPROT + 3) / 4, 256, 0, stream>>>(prot_x, g.nrm, g.slabs, NPROT);
  run_layer_prot<74, 50, false>(g, pW[0], pB[0], NPROT, stream);
  run_layer_prot<50, 45, false>(g, pW[1], pB[1], NPROT, stream);
  run_layer_prot<45, 45, true >(g, pW[2], pB[2], NPROT, stream);
  segmax_kernel<<<(NPROT + 255) / 256, 256, 0, stream>>>(g.X, prot_gid, rep, NPROT, 1);

  // ---- ligand GNN (small; fused path) ----
  build_csr(lig_src, lig_dst, g, NLIG, ELIG, stream);
  run_layer_lig<74, 96, 50>(lig_x, g, lW[0], lB[0], NLIG, stream);
  run_layer_lig<50, 64, 45>(g.X, g, lW[1], lB[1], NLIG, stream);
  run_layer_lig<45, 64, 45>(g.X, g, lW[2], lB[2], NLIG, stream);
  run_layer_lig<45, 64, 45>(g.X, g, lW[3], lB[3], NLIG, stream);
  segmax_kernel<<<(NLIG + 255) / 256, 256, 0, stream>>>(g.X, lig_gid, rep, NLIG, 0);

  // ---- attention ----
  qkv_kernel<<<130, 256, 0, stream>>>(rep, qkv_w, qkv_b, qkvb);
  attn_kernel<<<130, 256, 0, stream>>>(qkvb, proj_w, proj_b, ctx);

  // ---- head MLP ----
  bias_init_kernel<<<8, 256, 0, stream>>>(h0_b, hb0, 2000);
  fc_splitk_kernel<false><<<dim3(8, 8), 256, 0, stream>>>(ctx, h0_w, hb0, 5850, 2000, 732);
  bias_init_kernel<<<4, 256, 0, stream>>>(h1_b, hb1, 1000);
  fc_splitk_kernel<true><<<dim3(4, 4), 256, 0, stream>>>(hb0, h1_w, hb1, 2000, 1000, 500);
  bias_init_kernel<<<2, 256, 0, stream>>>(h2_b, hb2, 500);
  fc_splitk_kernel<true><<<dim3(2, 2), 256, 0, stream>>>(hb1, h2_w, hb2, 1000, 500, 500);
  final_fc_kernel<<<1, 512, 0, stream>>>(hb2, fc_w, fc_b, (float*)d_out);
}

// Round 10
// 1421.509 us; speedup vs baseline: 1.9459x; 1.0844x over previous
//
#include <hip/hip_runtime.h>
#include <hip/hip_fp16.h>
#include <cstddef>
#include <cstdint>

namespace {

constexpr int NPROT = 100000;
constexpr int EPROT = 1600000;
constexpr int NLIG  = 5000;
constexpr int ELIG  = 80000;

// ---------------- CSR construction ----------------

__global__ void hist_kernel(const int* __restrict__ dst, int* __restrict__ cnt, int e) {
  int i = blockIdx.x * 256 + threadIdx.x;
  if (i < e) atomicAdd(&cnt[dst[i]], 1);
}

// per-block (1024 elems) exclusive scan; also computes nrm = max(deg,1)^-0.5
__global__ void scan1_kernel(const int* __restrict__ cnt, int* __restrict__ rp,
                             int* __restrict__ bsum, float* __restrict__ nrm, int n) {
  __shared__ int wsum[4];
  int t = threadIdx.x;
  int base = blockIdx.x * 1024 + t * 4;
  int v0 = 0, v1 = 0, v2 = 0, v3 = 0;
  if (base + 3 < n) {
    int4 val = *(const int4*)(cnt + base);
    v0 = val.x; v1 = val.y; v2 = val.z; v3 = val.w;
  } else if (base < n) {
    v0 = cnt[base];
    if (base + 1 < n) v1 = cnt[base + 1];
    if (base + 2 < n) v2 = cnt[base + 2];
  }
  if (base < n)     nrm[base]     = 1.0f / sqrtf(fmaxf((float)v0, 1.0f));
  if (base + 1 < n) nrm[base + 1] = 1.0f / sqrtf(fmaxf((float)v1, 1.0f));
  if (base + 2 < n) nrm[base + 2] = 1.0f / sqrtf(fmaxf((float)v2, 1.0f));
  if (base + 3 < n) nrm[base + 3] = 1.0f / sqrtf(fmaxf((float)v3, 1.0f));
  int ts = v0 + v1 + v2 + v3;
  int lane = t & 63, wv = t >> 6;
  int incl = ts;
  #pragma unroll
  for (int off = 1; off < 64; off <<= 1) {
    int o = __shfl_up(incl, off, 64);
    if (lane >= off) incl += o;
  }
  if (lane == 63) wsum[wv] = incl;
  __syncthreads();
  int woff = 0;
  #pragma unroll
  for (int i = 0; i < 4; ++i) if (i < wv) woff += wsum[i];
  int excl = woff + incl - ts;
  int o0 = excl, o1 = o0 + v0, o2 = o1 + v1, o3 = o2 + v2;
  if (base + 3 < n) {
    *(int4*)(rp + base) = make_int4(o0, o1, o2, o3);
  } else if (base < n) {
    rp[base] = o0;
    if (base + 1 < n) rp[base + 1] = o1;
    if (base + 2 < n) rp[base + 2] = o2;
  }
  if (t == 255) bsum[blockIdx.x] = woff + incl;  // block total
}

// exclusive scan of <=256 block sums; writes grand total to rp[n]
__global__ void scan2_kernel(int* __restrict__ bsum, int nb, int* __restrict__ rp_end) {
  __shared__ int s[256];
  int t = threadIdx.x;
  int v = (t < nb) ? bsum[t] : 0;
  s[t] = v;
  __syncthreads();
  int val = v;
  for (int off = 1; off < 256; off <<= 1) {
    int add = (t >= off) ? s[t - off] : 0;
    __syncthreads();
    val += add;
    s[t] = val;
    __syncthreads();
  }
  if (t < nb) bsum[t] = val - v;  // exclusive
  if (t == 255) *rp_end = val;    // total
}

__global__ void scan3_kernel(int* __restrict__ rp, const int* __restrict__ bsum, int n) {
  int i = blockIdx.x * 256 + threadIdx.x;
  if (i < n) rp[i] += bsum[i >> 10];
}

__global__ void scatter_kernel(const int* __restrict__ src, const int* __restrict__ dst,
                               const int* __restrict__ rp, int* __restrict__ cur,
                               int* __restrict__ col, int e) {
  int i = blockIdx.x * 256 + threadIdx.x;
  if (i < e) {
    int d = dst[i];
    int p = rp[d] + atomicAdd(&cur[d], 1);
    col[p] = src[i];
  }
}

// ---------------- protein GNN ----------------
// g_k = nrm.*h_k stored fp16 in 16-feat chunks, padded width PD=ceil(DIN/16)*16
// (pads stay zero). Slab k (hop k) at gbase + k*slabh, slabh = n*80 halves.
// Chunk c, node v, slot s: addr = (c*n + v)*16 + s  (32B rows, L2-friendly).
// gathers: g_k = nrm^2 * sum_{src} g_{k-1}[src], one L2-resident chunk/pass.
// combine: block = 64 nodes; 4 waves each own a wave-uniform quarter of DOUT
// (W via scalar loads); cross-wave l2norm via LDS; writes next g0 in-place.

__device__ __forceinline__ float2 cvt_h2(uint32_t u) {
  __half2 h = *reinterpret_cast<__half2*>(&u);
  return make_float2(__low2float(h), __high2float(h));
}

// grid = NPASS*nbn (pass-major); 256 thr = 4 waves; wave = 4 nodes x 16 lanes
// (4 edge slots x 4 f4-lanes, 8B loads); 4 clamped branch-free loads in flight.
__global__ void gather_all_kernel(const __half* __restrict__ gin, const int* __restrict__ rp,
                                  const int* __restrict__ col, const float* __restrict__ nrm,
                                  __half* __restrict__ gout, int n, int nbn) {
  int pass = blockIdx.x / nbn;
  int bid = blockIdx.x - pass * nbn;
  int lane = threadIdx.x & 63, wv = threadIdx.x >> 6;
  int q = lane >> 4, r = lane & 15;
  int e_slot = r >> 2, f4 = r & 3;
  int v = bid * 16 + wv * 4 + q;
  bool vok = (v < n);
  int beg = 0, deg = 0;
  if (vok) { beg = rp[v]; deg = rp[v + 1] - beg; }
  const __half* gc = gin + (size_t)pass * n * 16;
  __half* go = gout + (size_t)pass * n * 16;
  float a0 = 0.f, a1 = 0.f, a2 = 0.f, a3 = 0.f;
  for (int base = 0; __any(base < deg); base += 16) {
    int ec = (base + r < deg) ? col[beg + base + r] : -1;
    #pragma unroll
    for (int js = 0; js < 16; js += 4) {
      int sl = (q << 4) + js + e_slot;
      int s0 = __shfl(ec, sl, 64);
      int idx = (s0 >= 0) ? s0 : 0;             // clamped: row 0 when invalid
      float m = (s0 >= 0) ? 1.f : 0.f;
      uint2 u = *(const uint2*)(gc + (size_t)idx * 16 + (f4 << 2));
      float2 p0 = cvt_h2(u.x), p1 = cvt_h2(u.y);
      a0 += m * p0.x; a1 += m * p0.y; a2 += m * p1.x; a3 += m * p1.y;
    }
  }
  a0 += __shfl_xor(a0, 4, 64);  a1 += __shfl_xor(a1, 4, 64);
  a2 += __shfl_xor(a2, 4, 64);  a3 += __shfl_xor(a3, 4, 64);
  a0 += __shfl_xor(a0, 8, 64);  a1 += __shfl_xor(a1, 8, 64);
  a2 += __shfl_xor(a2, 8, 64);  a3 += __shfl_xor(a3, 8, 64);
  if (vok && e_slot == 0) {
    float nm = nrm[v];
    float nm2 = nm * nm;
    __half2 w0 = __floats2half2_rn(a0 * nm2, a1 * nm2);
    __half2 w1 = __floats2half2_rn(a2 * nm2, a3 * nm2);
    uint2 st;
    st.x = *reinterpret_cast<uint32_t*>(&w0);
    st.y = *reinterpret_cast<uint32_t*>(&w1);
    *(uint2*)(go + ((size_t)v << 4) + (f4 << 2)) = st;
  }
}

// layer-1 only: g0 = x * nrm (chunked, pads zero)
template<int DIN>
__global__ void init_g0_kernel(const float* __restrict__ x, const float* __restrict__ nrm,
                               __half* __restrict__ g0, int n) {
  constexpr int PD = (DIN + 15) & ~15;
  int lane = threadIdx.x & 63;
  int v = blockIdx.x * 4 + (threadIdx.x >> 6);
  if (v >= n) return;
  float nm = nrm[v];
  for (int f = lane; f < PD; f += 64) {
    float val = (f < DIN) ? x[(size_t)v * DIN + f] * nm : 0.f;
    g0[(((size_t)(f >> 4) * n + v) << 4) + (f & 15)] = __float2half(val);
  }
}

// pad W [5*DIN][DOUT] -> Wp [5*PD][DOUT] (pad rows zero)
__global__ void padw_kernel(const float* __restrict__ W, float* __restrict__ Wp,
                            int din, int dout, int pd) {
  int i = blockIdx.x * 256 + threadIdx.x;
  int total = 5 * pd * dout;
  if (i >= total) return;
  int f = i / dout, j = i - f * dout;
  int hop = f / pd, rem = f - hop * pd;
  Wp[i] = (rem < din) ? W[(size_t)(hop * din + rem) * dout + j] : 0.f;
}

// combine v4: block = 64 nodes, wave wv owns outputs [wv*QO, ...) (wave-uniform
// column offset -> W/bias scalar loads). Cross-wave l2norm via LDS ssq.
template<int DIN, int DOUT, bool LAST>
__global__ __launch_bounds__(256) void combine_kernel(
    const __half* __restrict__ gbase, const float* __restrict__ nrm,
    const float* __restrict__ Wp, const float* __restrict__ bias,
    __half* __restrict__ gnext, float* __restrict__ Xout, int n) {
  constexpr int PD  = (DIN + 15) & ~15;
  constexpr int NCH = PD / 16;
  constexpr int PDN = (DOUT + 15) & ~15;
  constexpr int QO  = ((DOUT + 7) / 8) * 2;   // even, 4*QO >= DOUT
  __shared__ float ssq[4 * 64];
  int lane = threadIdx.x & 63, wv = threadIdx.x >> 6;
  int v = blockIdx.x * 64 + lane;
  bool vok = (v < n);
  int vc = vok ? v : 0;
  const size_t slabh = (size_t)n * 80;
  int cofs = __builtin_amdgcn_readfirstlane(wv) * QO;   // wave-uniform
  float acc[QO];
  #pragma unroll
  for (int jj = 0; jj < QO; ++jj) acc[jj] = 0.f;
  const float* wb = Wp + cofs;
  for (int hop = 0; hop < 5; ++hop) {
    const __half* hrow = gbase + (size_t)hop * slabh + ((size_t)vc << 4);
    #pragma unroll 1
    for (int ch = 0; ch < NCH; ++ch) {
      uint4 u0 = *(const uint4*)hrow;
      uint4 u1 = *(const uint4*)(hrow + 8);
      float h[16];
      {
        float2 p;
        p = cvt_h2(u0.x); h[0] = p.x; h[1] = p.y;
        p = cvt_h2(u0.y); h[2] = p.x; h[3] = p.y;
        p = cvt_h2(u0.z); h[4] = p.x; h[5] = p.y;
        p = cvt_h2(u0.w); h[6] = p.x; h[7] = p.y;
        p = cvt_h2(u1.x); h[8] = p.x; h[9] = p.y;
        p = cvt_h2(u1.y); h[10] = p.x; h[11] = p.y;
        p = cvt_h2(u1.z); h[12] = p.x; h[13] = p.y;
        p = cvt_h2(u1.w); h[14] = p.x; h[15] = p.y;
      }
      #pragma unroll
      for (int s = 0; s < 16; ++s) {
        #pragma unroll
        for (int jj = 0; jj < QO; ++jj) acc[jj] += h[s] * wb[s * DOUT + jj];
      }
      wb += 16 * DOUT;
      hrow += ((size_t)n << 4);
    }
  }
  float rn = 1.f / nrm[vc];
  float ss = 0.f;
  #pragma unroll
  for (int jj = 0; jj < QO; ++jj) {
    int j = cofs + jj;
    float y = (j < DOUT) ? fmaxf(bias[j] + acc[jj] * rn, 0.f) : 0.f;
    acc[jj] = y;
    ss += y * y;
  }
  ssq[wv * 64 + lane] = ss;
  __syncthreads();          // also orders all slab-0 reads before in-place writes
  if (!vok) return;
  float tot = ssq[lane] + ssq[64 + lane] + ssq[128 + lane] + ssq[192 + lane];
  float sc = 1.f / fmaxf(sqrtf(tot), 1e-12f);
  if (LAST) {
    #pragma unroll
    for (int jj = 0; jj < QO; ++jj) {
      int j = cofs + jj;
      if (j < DOUT) Xout[(size_t)v * DOUT + j] = acc[jj] * sc;
    }
  } else {
    float nm = nrm[v];
    #pragma unroll
    for (int jj = 0; jj < QO; jj += 2) {
      int j0 = cofs + jj;
      float a = (j0 < DOUT) ? acc[jj] * sc * nm : 0.f;
      float b = (j0 + 1 < DOUT) ? acc[jj + 1] * sc * nm : 0.f;
      int ch = j0 >> 4, s = j0 & 15;
      *(__half2*)(gnext + (((size_t)ch * n + v) << 4) + s) = __floats2half2_rn(a, b);
    }
    if (wv == 3) {
      #pragma unroll
      for (int j0 = 4 * QO; j0 < PDN; j0 += 2) {    // zero-fill padded tail
        int ch = j0 >> 4, s = j0 & 15;
        *(__half2*)(gnext + (((size_t)ch * n + v) << 4) + s) = __floats2half2_rn(0.f, 0.f);
      }
    }
  }
}

// ---------------- ligand GNN: small-n fused hop (g is L2-resident) --------

template<int DIN, int GS, int DOUT>
__global__ void init_gemm_kernel(const float* __restrict__ x, const float* __restrict__ nrm,
                                 const float* __restrict__ W, const float* __restrict__ bias,
                                 __half* __restrict__ gout, float* __restrict__ y, int n) {
  int lane = threadIdx.x & 63;
  int v = blockIdx.x * 4 + (threadIdx.x >> 6);
  if (v >= n) return;
  float nm = nrm[v];
  const float* xr = x + (size_t)v * DIN;
  float hA = (lane < DIN) ? xr[lane] : 0.f;
  float hB = 0.f;
  if constexpr (DIN > 64) { if (lane + 64 < DIN) hB = xr[lane + 64]; }
  __half* go = gout + (size_t)v * GS;
  if (lane < DIN) go[lane] = __float2half(hA * nm);
  if constexpr (DIN > 64) { if (lane + 64 < DIN) go[lane + 64] = __float2half(hB * nm); }
  int cl = (lane < DOUT) ? lane : 0;
  float acc = bias[cl];
  const float* Wk = W + cl;
  #pragma unroll
  for (int f = 0; f < DIN; ++f) {
    float hf = (f < 64) ? __shfl(hA, f, 64) : __shfl(hB, f - 64, 64);
    acc += hf * Wk[(size_t)f * DOUT];
  }
  if (lane < DOUT) y[(size_t)v * DOUT + lane] = acc;
}

template<int DIN, int GS, int DOUT, bool WRITEG, bool FINAL>
__global__ void fused_hop_kernel(const __half* __restrict__ gin, const int* __restrict__ rp,
                                 const int* __restrict__ col, const float* __restrict__ nrm,
                                 const float* __restrict__ W, __half* __restrict__ gout,
                                 float* __restrict__ y, float* __restrict__ Xout,
                                 int k, int n) {
  int lane = threadIdx.x & 63;
  int v = blockIdx.x * 4 + (threadIdx.x >> 6);
  if (v >= n) return;
  int beg = rp[v], end = rp[v + 1];
  float a0 = 0.f, a1 = 0.f;
  for (int base = beg; base < end; base += 64) {
    int m = end - base; if (m > 64) m = 64;
    int myc = (lane < m) ? col[base + lane] : 0;
    int j = 0;
    for (; j + 8 <= m; j += 8) {
      int ss[8];
      float t0[8], t1[8];
      #pragma unroll
      for (int u = 0; u < 8; ++u) ss[u] = __shfl(myc, j + u, 64);
      #pragma unroll
      for (int u = 0; u < 8; ++u) {
        const __half* rr = gin + (size_t)ss[u] * GS;
        t0[u] = (lane < DIN) ? __half2float(rr[lane]) : 0.f;
        if constexpr (DIN > 64) t1[u] = (lane + 64 < DIN) ? __half2float(rr[lane + 64]) : 0.f;
      }
      #pragma unroll
      for (int u = 0; u < 8; ++u) {
        a0 += t0[u];
        if constexpr (DIN > 64) a1 += t1[u];
      }
    }
    for (; j < m; ++j) {
      int s = __shfl(myc, j, 64);
      const __half* rr = gin + (size_t)s * GS;
      if (lane < DIN) a0 += __half2float(rr[lane]);
      if constexpr (DIN > 64) { if (lane + 64 < DIN) a1 += __half2float(rr[lane + 64]); }
    }
  }
  float nm = nrm[v];
  float hA = a0 * nm, hB = a1 * nm;
  if (WRITEG) {
    __half* go = gout + (size_t)v * GS;
    if (lane < DIN) go[lane] = __float2half(hA * nm);
    if constexpr (DIN > 64) { if (lane + 64 < DIN) go[lane + 64] = __float2half(hB * nm); }
  }
  int cl = (lane < DOUT) ? lane : 0;
  float acc = 0.f;
  if (lane < DOUT) acc = y[(size_t)v * DOUT + lane];
  const float* Wk = W + (size_t)k * DIN * DOUT + cl;
  #pragma unroll
  for (int f = 0; f < DIN; ++f) {
    float hf = (f < 64) ? __shfl(hA, f, 64) : __shfl(hB, f - 64, 64);
    acc += hf * Wk[(size_t)f * DOUT];
  }
  if constexpr (FINAL) {
    float val = (lane < DOUT) ? fmaxf(acc, 0.f) : 0.f;
    float ss2 = val * val;
    #pragma unroll
    for (int off2 = 32; off2 > 0; off2 >>= 1) ss2 += __shfl_xor(ss2, off2, 64);
    float scale = 1.f / fmaxf(sqrtf(ss2), 1e-12f);
    if (lane < DOUT) Xout[(size_t)v * DOUT + lane] = val * scale;
  } else {
    if (lane < DOUT) y[(size_t)v * DOUT + lane] = acc;
  }
}

// hierarchical segment-max (values >= 0 post relu+l2norm; rep zeroed first)
__global__ void segmax_kernel(const float* __restrict__ X, const int* __restrict__ gid,
                              float* __restrict__ rep, int n, int row_off) {
  __shared__ float tab[4][45];
  __shared__ int gids[256];
  int t = threadIdx.x;
  for (int i = t; i < 4 * 45; i += 256) ((float*)tab)[i] = 0.f;
  int v0 = blockIdx.x * 256;
  int vend = v0 + 256; if (vend > n) vend = n;
  int nv = vend - v0;
  if (t < nv) gids[t] = gid[v0 + t];
  __syncthreads();
  int g0 = gids[0];
  int total = nv * 45;
  for (int i = t; i < total; i += 256) {
    int vl = i / 45, j = i - vl * 45;
    float val = X[(size_t)(v0 + vl) * 45 + j];
    int rel = gids[vl] - g0;
    if (rel >= 0 && rel < 4)
      atomicMax((unsigned int*)&tab[rel][j], __float_as_uint(val));
    else
      atomicMax((unsigned int*)&rep[(size_t)(row_off + gids[vl]) * 45 + j], __float_as_uint(val));
  }
  __syncthreads();
  for (int i = t; i < 4 * 45; i += 256) {
    float val = ((float*)tab)[i];
    if (val > 0.f) {
      int rel = i / 45, j = i - rel * 45;
      atomicMax((unsigned int*)&rep[(size_t)(row_off + g0 + rel) * 45 + j], __float_as_uint(val));
    }
  }
}

// ---------------- attention ----------------

__global__ void qkv_kernel(const float* __restrict__ rep, const float* __restrict__ w,
                           const float* __restrict__ b, float* __restrict__ qkv) {
  int i = blockIdx.x;      // 0..129
  int t = threadIdx.x;     // 256
  __shared__ float sr[45];
  if (t < 45) sr[t] = (i < 65) ? rep[(size_t)i * 45 + t] : 0.f;
  __syncthreads();
  if (t < 135) {
    float acc = b[t];
    #pragma unroll 5
    for (int d = 0; d < 45; ++d) acc += sr[d] * w[d * 135 + t];
    qkv[(size_t)i * 135 + t] = acc;
  }
}

__global__ void attn_kernel(const float* __restrict__ qkv, const float* __restrict__ proj_w,
                            const float* __restrict__ proj_b, float* __restrict__ ctx) {
  int i = blockIdx.x;     // query row
  int t = threadIdx.x;    // 256
  __shared__ float q[45];
  __shared__ float p[130];
  __shared__ float red[256];
  __shared__ float ao[45];
  if (t < 45) q[t] = qkv[(size_t)i * 135 + t];
  __syncthreads();
  float s = -1e30f;
  if (t < 130) {
    int j = t;
    float dot = 0.f;
    #pragma unroll 5
    for (int d = 0; d < 45; ++d) dot += q[d] * qkv[(size_t)j * 135 + 45 + d];
    dot *= 0.14907119849998599f;  // 45^-0.5
    bool mz;  // mask == 0 ?
    if (i == 64 && j == 64) mz = true;
    else if (i == 64 || j == 64) mz = false;
    else mz = !(i == j && i < 65);
    s = mz ? -1e9f : dot;
  }
  red[t] = s;
  __syncthreads();
  #pragma unroll
  for (int off = 128; off > 0; off >>= 1) {
    if (t < off) red[t] = fmaxf(red[t], red[t + off]);
    __syncthreads();
  }
  float mx = red[0];
  __syncthreads();
  float e = (t < 130) ? expf(s - mx) : 0.f;
  red[t] = e;
  __syncthreads();
  #pragma unroll
  for (int off = 128; off > 0; off >>= 1) {
    if (t < off) red[t] += red[t + off];
    __syncthreads();
  }
  float denom = red[0];
  __syncthreads();
  if (t < 130) p[t] = e / denom;
  __syncthreads();
  if (t < 45) {
    float acc = 0.f;
    for (int j = 0; j < 130; ++j) acc += p[j] * qkv[(size_t)j * 135 + 90 + t];
    ao[t] = acc;
  }
  __syncthreads();
  if (t < 45) {
    float pr = proj_b[t];
    #pragma unroll 5
    for (int e2 = 0; e2 < 45; ++e2) pr += ao[e2] * proj_w[e2 * 45 + t];
    ctx[(size_t)i * 45 + t] = pr;
  }
}

// ---------------- head MLP ----------------

__global__ void bias_init_kernel(const float* __restrict__ b, float* __restrict__ out, int n) {
  int i = blockIdx.x * 256 + threadIdx.x;
  if (i < n) out[i] = b[i];
}

template<bool RELU_IN>
__global__ void fc_splitk_kernel(const float* __restrict__ x, const float* __restrict__ W,
                                 float* __restrict__ out, int nin, int nout, int kchunk) {
  __shared__ float xs[1024];
  int k0 = blockIdx.y * kchunk;
  int k1 = k0 + kchunk; if (k1 > nin) k1 = nin;
  int len = k1 - k0;
  for (int i = threadIdx.x; i < len; i += blockDim.x) {
    float v = x[k0 + i];
    xs[i] = RELU_IN ? fmaxf(v, 0.f) : v;
  }
  __syncthreads();
  int j = blockIdx.x * blockDim.x + threadIdx.x;
  if (j < nout) {
    float acc = 0.f;
    const float* Wp = W + (size_t)k0 * nout + j;
    for (int i = 0; i < len; ++i) acc += xs[i] * Wp[(size_t)i * nout];
    atomicAdd(&out[j], acc);
  }
}

__global__ void final_fc_kernel(const float* __restrict__ x, const float* __restrict__ W,
                                const float* __restrict__ b, float* __restrict__ out) {
  __shared__ float red[512];
  int t = threadIdx.x;
  float acc = 0.f;
  if (t < 500) acc = fmaxf(x[t], 0.f) * W[t];
  red[t] = acc;
  __syncthreads();
  #pragma unroll
  for (int off = 256; off > 0; off >>= 1) {
    if (t < off) red[t] += red[t + off];
    __syncthreads();
  }
  if (t == 0) {
    float z = red[0] + b[0];
    out[0] = 1.f / (1.f + expf(-z));
  }
}

// ---------------- host-side orchestration ----------------

struct Bufs {
  __half* slabs;         // protein: 5 slabs of n*80 halves
  __half *ligA, *ligB;   // ligand ping/pong
  float *X, *Y, *nrm, *Wp;
  int *cnt, *cur, *rp, *col, *bsum;
};

template<int DIN, int DOUT, bool LAST>
void run_layer_prot(const Bufs& g, const float* W, const float* b, int n, hipStream_t st) {
  constexpr int PD = (DIN + 15) & ~15;
  constexpr int NPASS = PD / 16;
  int nbn = (n + 15) / 16;
  size_t slabh = (size_t)n * 80;
  for (int k = 1; k <= 4; ++k)
    gather_all_kernel<<<NPASS * nbn, 256, 0, st>>>(g.slabs + (size_t)(k - 1) * slabh,
                                                   g.rp, g.col, g.nrm,
                                                   g.slabs + (size_t)k * slabh, n, nbn);
  int wtotal = 5 * PD * DOUT;
  padw_kernel<<<(wtotal + 255) / 256, 256, 0, st>>>(W, g.Wp, DIN, DOUT, PD);
  combine_kernel<DIN, DOUT, LAST><<<(n + 63) / 64, 256, 0, st>>>(
      g.slabs, g.nrm, g.Wp, b, g.slabs, g.X, n);
}

template<int DIN, int GS, int DOUT>
void run_layer_lig(const float* xin, const Bufs& g, const float* W, const float* b,
                   int n, hipStream_t st) {
  int nb = (n + 3) / 4;
  init_gemm_kernel<DIN, GS, DOUT><<<nb, 256, 0, st>>>(xin, g.nrm, W, b, g.ligA, g.Y, n);
  const __half* gin = g.ligA;
  __half* gout = g.ligB;
  for (int k = 1; k <= 4; ++k) {
    if (k < 4)
      fused_hop_kernel<DIN, GS, DOUT, true, false><<<nb, 256, 0, st>>>(gin, g.rp, g.col, g.nrm, W, gout, g.Y, g.X, k, n);
    else
      fused_hop_kernel<DIN, GS, DOUT, false, true><<<nb, 256, 0, st>>>(gin, g.rp, g.col, g.nrm, W, gout, g.Y, g.X, 4, n);
    __half* t = (__half*)gin; gin = gout; gout = t;
  }
}

void build_csr(const int* src, const int* dst, const Bufs& g, int n, int e, hipStream_t st) {
  hipMemsetAsync(g.cnt, 0, (size_t)n * 4, st);
  hipMemsetAsync(g.cur, 0, (size_t)n * 4, st);
  hist_kernel<<<(e + 255) / 256, 256, 0, st>>>(dst, g.cnt, e);
  int nb1 = (n + 1023) / 1024;
  scan1_kernel<<<nb1, 256, 0, st>>>(g.cnt, g.rp, g.bsum, g.nrm, n);
  scan2_kernel<<<1, 256, 0, st>>>(g.bsum, nb1, g.rp + n);
  scan3_kernel<<<(n + 255) / 256, 256, 0, st>>>(g.rp, g.bsum, n);
  scatter_kernel<<<(e + 255) / 256, 256, 0, st>>>(src, dst, g.rp, g.cur, g.col, e);
}

} // namespace

extern "C" void kernel_launch(void* const* d_in, const int* in_sizes, int n_in,
                              void* d_out, int out_size, void* d_ws, size_t ws_size,
                              hipStream_t stream) {
  (void)in_sizes; (void)n_in; (void)out_size;

  const float* prot_x = (const float*)d_in[0];
  const float* lig_x  = (const float*)d_in[1];
  const float* pW[3] = {(const float*)d_in[2], (const float*)d_in[4], (const float*)d_in[6]};
  const float* pB[3] = {(const float*)d_in[3], (const float*)d_in[5], (const float*)d_in[7]};
  const float* lW[4] = {(const float*)d_in[8], (const float*)d_in[10], (const float*)d_in[12], (const float*)d_in[14]};
  const float* lB[4] = {(const float*)d_in[9], (const float*)d_in[11], (const float*)d_in[13], (const float*)d_in[15]};
  const float* qkv_w = (const float*)d_in[16];
  const float* qkv_b = (const float*)d_in[17];
  const float* proj_w = (const float*)d_in[18];
  const float* proj_b = (const float*)d_in[19];
  const float* h0_w = (const float*)d_in[20];
  const float* h0_b = (const float*)d_in[21];
  const float* h1_w = (const float*)d_in[22];
  const float* h1_b = (const float*)d_in[23];
  const float* h2_w = (const float*)d_in[24];
  const float* h2_b = (const float*)d_in[25];
  const float* fc_w = (const float*)d_in[26];
  const float* fc_b = (const float*)d_in[27];
  const int* prot_src = (const int*)d_in[28];
  const int* prot_dst = (const int*)d_in[29];
  const int* prot_gid = (const int*)d_in[30];
  const int* lig_src  = (const int*)d_in[31];
  const int* lig_dst  = (const int*)d_in[32];
  const int* lig_gid  = (const int*)d_in[33];

  // workspace carve-up
  char* w = (char*)d_ws;
  size_t off = 0;
  auto alloc = [&](size_t bytes) -> void* {
    void* p = w + off;
    off += (bytes + 255) & ~(size_t)255;
    return p;
  };
  __half* slabs = (__half*)alloc((size_t)5 * NPROT * 80 * 2);   // 80 MB: g0..g4
  __half* ligA  = (__half*)alloc((size_t)NLIG * 96 * 2);
  __half* ligB  = (__half*)alloc((size_t)NLIG * 96 * 2);
  float* X   = (float*)alloc((size_t)NPROT * 45 * 4);
  float* Y   = (float*)alloc((size_t)NLIG * 50 * 4);
  float* nrm = (float*)alloc((size_t)NPROT * 4);
  float* Wp  = (float*)alloc((size_t)5 * 80 * 50 * 4 + 256);  // + scalar-OOB pad
  int* cnt   = (int*)alloc((size_t)NPROT * 4);
  int* cur   = (int*)alloc((size_t)NPROT * 4);
  int* rp    = (int*)alloc(((size_t)NPROT + 1) * 4);
  int* colb  = (int*)alloc((size_t)EPROT * 4);
  int* bsum  = (int*)alloc((size_t)256 * 4);
  float* rep = (float*)alloc((size_t)65 * 45 * 4);
  float* qkvb = (float*)alloc((size_t)130 * 135 * 4);
  float* ctx  = (float*)alloc((size_t)5850 * 4);
  float* hb0  = (float*)alloc((size_t)2000 * 4);
  float* hb1  = (float*)alloc((size_t)1000 * 4);
  float* hb2  = (float*)alloc((size_t)500 * 4);
  if (off > ws_size) return;  // workspace too small: fail loudly via validation

  hipMemsetAsync(rep, 0, (size_t)65 * 45 * 4, stream);

  Bufs g{slabs, ligA, ligB, X, Y, nrm, Wp, cnt, cur, rp, colb, bsum};

  // ---- protein GNN (chunked L2-resident gathers + wave-split combine) ----
  build_csr(prot_src, prot_dst, g, NPROT, EPROT, stream);
  init_g0_kernel<74><<<(NPROT + 3) / 4, 256, 0, stream>>>(prot_x, g.nrm, g.slabs, NPROT);
  run_layer_prot<74, 50, false>(g, pW[0], pB[0], NPROT, stream);
  run_layer_prot<50, 45, false>(g, pW[1], pB[1], NPROT, stream);
  run_layer_prot<45, 45, true >(g, pW[2], pB[2], NPROT, stream);
  segmax_kernel<<<(NPROT + 255) / 256, 256, 0, stream>>>(g.X, prot_gid, rep, NPROT, 1);

  // ---- ligand GNN (small; fused path) ----
  build_csr(lig_src, lig_dst, g, NLIG, ELIG, stream);
  run_layer_lig<74, 96, 50>(lig_x, g, lW[0], lB[0], NLIG, stream);
  run_layer_lig<50, 64, 45>(g.X, g, lW[1], lB[1], NLIG, stream);
  run_layer_lig<45, 64, 45>(g.X, g, lW[2], lB[2], NLIG, stream);
  run_layer_lig<45, 64, 45>(g.X, g, lW[3], lB[3], NLIG, stream);
  segmax_kernel<<<(NLIG + 255) / 256, 256, 0, stream>>>(g.X, lig_gid, rep, NLIG, 0);

  // ---- attention ----
  qkv_kernel<<<130, 256, 0, stream>>>(rep, qkv_w, qkv_b, qkvb);
  attn_kernel<<<130, 256, 0, stream>>>(qkvb, proj_w, proj_b, ctx);

  // ---- head MLP ----
  bias_init_kernel<<<8, 256, 0, stream>>>(h0_b, hb0, 2000);
  fc_splitk_kernel<false><<<dim3(8, 8), 256, 0, stream>>>(ctx, h0_w, hb0, 5850, 2000, 732);
  bias_init_kernel<<<4, 256, 0, stream>>>(h1_b, hb1, 1000);
  fc_splitk_kernel<true><<<dim3(4, 4), 256, 0, stream>>>(hb0, h1_w, hb1, 2000, 1000, 500);
  bias_init_kernel<<<2, 256, 0, stream>>>(h2_b, hb2, 500);
  fc_splitk_kernel<true><<<dim3(2, 2), 256, 0, stream>>>(hb1, h2_w, hb2, 1000, 500, 500);
  final_fc_kernel<<<1, 512, 0, stream>>>(hb2, fc_w, fc_b, (float*)d_out);
}